// Round 7
// baseline (204.356 us; speedup 1.0000x reference)
//
#include <hip/hip_runtime.h>

#define N_NODES 100000
#define N_EDGES 1600000
#define IN_F 128
#define H_F 64
#define ZROW N_NODES    // zero sentinel row index in gather tables

#define BSH 10          // coarse bucket = dst >> 10
#define BNODES 1024     // nodes per bucket
#define NBKT 98         // ceil(100000 / 1024)
#define EPB 4096        // edges per block in coarse scatter

typedef short short8 __attribute__((ext_vector_type(8)));
typedef float floatx4 __attribute__((ext_vector_type(4)));

union U16x8 { short8 v; unsigned short us[8]; unsigned int u[4]; };

// ---- bf16 helpers ----
static __device__ __forceinline__ unsigned short f2bf(float f) {
    unsigned int u = __float_as_uint(f);
    unsigned int r = (u + 0x7FFFu + ((u >> 16) & 1u)) >> 16;
    return (unsigned short)r;
}
static __device__ __forceinline__ float bf2f(unsigned short v) {
    return __uint_as_float(((unsigned int)v) << 16);
}
static __device__ __forceinline__ float bflo(unsigned int u) {
    return __uint_as_float(u << 16);
}
static __device__ __forceinline__ float bfhi(unsigned int u) {
    return __uint_as_float(u & 0xFFFF0000u);
}
static __device__ __forceinline__ unsigned int pk2(float a, float b) {
    return (unsigned int)f2bf(a) | ((unsigned int)f2bf(b) << 16);
}

// ---------------- W fragment pre-pack ----------------
__global__ __launch_bounds__(256) void wpack_kernel(const float* __restrict__ W,
                                                    unsigned int* __restrict__ wfrag) {
    int i = blockIdx.x * 256 + threadIdx.x;   // [0, 8192)
    int reg = i & 3, lane = (i >> 2) & 63, fkc = i >> 8;
    int ct = fkc >> 2, kc = fkc & 3;
    int fcol = ct * 16 + (lane & 15);
    int k = kc * 32 + (lane >> 4) * 8 + reg * 2;
    wfrag[i] = pk2(W[k * 64 + fcol], W[(k + 1) * 64 + fcol]);
}

// ---------------- coarse histogram ----------------
__global__ __launch_bounds__(256) void hist_kernel(const int* __restrict__ dst,
                                                   int* __restrict__ ccnt, int E) {
    __shared__ int lh[4 * NBKT];
    int w = threadIdx.x >> 6;
    for (int i = threadIdx.x; i < 4 * NBKT; i += 256) lh[i] = 0;
    __syncthreads();
    int stride = gridDim.x * blockDim.x;
    for (int i = blockIdx.x * blockDim.x + threadIdx.x; i < E; i += stride)
        atomicAdd(&lh[w * NBKT + (dst[i] >> BSH)], 1);
    __syncthreads();
    for (int b = threadIdx.x; b < NBKT; b += 256) {
        int s = lh[b] + lh[NBKT + b] + lh[2 * NBKT + b] + lh[3 * NBKT + b];
        if (s) atomicAdd(&ccnt[b], s);
    }
}

// ---------------- coarse offsets + sentinel ----------------
__global__ void scan_coarse_kernel(const int* __restrict__ ccnt,
                                   int* __restrict__ cofs, int* __restrict__ ccur,
                                   int* __restrict__ offsets, int E) {
    if (threadIdx.x == 0) {
        int run = 0;
        for (int b = 0; b < NBKT; ++b) { cofs[b] = run; ccur[b] = run; run += ccnt[b]; }
        cofs[NBKT] = run;              // == E
        offsets[N_NODES] = E;          // sentinel for prop kernels
    }
}

// ---------------- pass 1: coarse scatter, packed (local_dst<<17 | src) ----------------
__global__ __launch_bounds__(256) void coarse_scatter_kernel(const int* __restrict__ src,
                                                             const int* __restrict__ dst,
                                                             int* __restrict__ ccur,
                                                             unsigned int* __restrict__ tmp, int E) {
    __shared__ unsigned int buf[EPB];               // 16 KB
    __shared__ unsigned char bktA[EPB];             // 4 KB
    __shared__ int cnt[NBKT], lofs[NBKT], gofs[NBKT];
    int base = blockIdx.x * EPB;
    int n = E - base; if (n > EPB) n = EPB;

    for (int i = threadIdx.x; i < NBKT; i += 256) cnt[i] = 0;
    __syncthreads();

    unsigned int v[16]; int bk[16], loc[16];
    #pragma unroll
    for (int j = 0; j < 16; ++j) {
        int o = threadIdx.x + j * 256;
        bk[j] = -1;
        if (o < n) {
            int s = src[base + o];
            int d = dst[base + o];
            bk[j]  = d >> BSH;
            v[j]   = ((unsigned int)(d & (BNODES - 1)) << 17) | (unsigned int)s;
            loc[j] = atomicAdd(&cnt[bk[j]], 1);
        }
    }
    __syncthreads();
    if (threadIdx.x == 0) {
        int run = 0;
        for (int b = 0; b < NBKT; ++b) { lofs[b] = run; run += cnt[b]; }
    }
    __syncthreads();
    if (threadIdx.x < NBKT && cnt[threadIdx.x] > 0)
        gofs[threadIdx.x] = atomicAdd(&ccur[threadIdx.x], cnt[threadIdx.x]);
    __syncthreads();
    #pragma unroll
    for (int j = 0; j < 16; ++j)
        if (bk[j] >= 0) {
            int p = lofs[bk[j]] + loc[j];
            buf[p]  = v[j];
            bktA[p] = (unsigned char)bk[j];
        }
    __syncthreads();
    for (int i = threadIdx.x; i < n; i += 256) {
        int b = bktA[i];
        tmp[gofs[b] + (i - lofs[b])] = buf[i];
    }
}

// ---------------- pass 2: per-bucket LDS pipeline ----------------
__global__ __launch_bounds__(512) void bucket_kernel(const unsigned int* __restrict__ tmp,
                                                     const int* __restrict__ cofs,
                                                     int* __restrict__ offsets,
                                                     int* __restrict__ sorted_src,
                                                     float* __restrict__ dinv1,
                                                     float* __restrict__ dinv2, int N) {
    __shared__ int cnt[BNODES];
    __shared__ int sd[512];
    int b   = blockIdx.x;
    int tid = threadIdx.x;
    int beg = cofs[b], end = cofs[b + 1];

    for (int i = tid; i < BNODES; i += 512) cnt[i] = 0;
    __syncthreads();
    for (int i = beg + tid; i < end; i += 512)
        atomicAdd(&cnt[tmp[i] >> 17], 1);
    __syncthreads();

    int c0 = cnt[2 * tid], c1 = cnt[2 * tid + 1];
    int s  = c0 + c1;
    sd[tid] = s;
    __syncthreads();
    for (int off = 1; off < 512; off <<= 1) {
        int t = (tid >= off) ? sd[tid - off] : 0;
        __syncthreads();
        sd[tid] += t;
        __syncthreads();
    }
    int ex = sd[tid] - s;
    int g0 = beg + ex, g1 = beg + ex + c0;

    int node0 = b * BNODES + 2 * tid;
    if (node0 < N) {
        offsets[node0] = g0;
        dinv1[node0] = rsqrtf((float)(c0 + 1));
        dinv2[node0] = c0 ? rsqrtf((float)c0) : 0.0f;
    }
    if (node0 + 1 < N) {
        offsets[node0 + 1] = g1;
        dinv1[node0 + 1] = rsqrtf((float)(c1 + 1));
        dinv2[node0 + 1] = c1 ? rsqrtf((float)c1) : 0.0f;
    }
    __syncthreads();
    cnt[2 * tid] = g0;
    cnt[2 * tid + 1] = g1;
    __syncthreads();

    for (int i = beg + tid; i < end; i += 512) {
        unsigned int v = tmp[i];
        int p = atomicAdd(&cnt[v >> 17], 1);
        sorted_src[p] = (int)(v & 0x1FFFFu);
    }
}

// ---------------- MFMA GEMM: Xs = bf16((in_feat @ W1) * dinv1) ----------------
__global__ __launch_bounds__(256) void gemm_kernel(const float* __restrict__ A,
                                                   const uint4* __restrict__ wfrag,
                                                   const float* __restrict__ dinv1,
                                                   unsigned short* __restrict__ Xs, int nTiles) {
    int wid = blockIdx.x * 4 + (threadIdx.x >> 6);
    if (wid >= nTiles) return;
    int lane = threadIdx.x & 63;
    int lrow = lane & 15, lk = lane >> 4;

    short8 wf[16];
    #pragma unroll
    for (int i = 0; i < 16; ++i)
        wf[i] = *reinterpret_cast<const short8*>(&wfrag[i * 64 + lane]);

    int node = wid * 16 + lrow;
    const float4* ap = reinterpret_cast<const float4*>(A + (size_t)node * IN_F);

    short8 af[4];
    #pragma unroll
    for (int kc = 0; kc < 4; ++kc) {
        float4 x = ap[kc * 8 + lk * 2];
        float4 y = ap[kc * 8 + lk * 2 + 1];
        U16x8 u;
        u.us[0] = f2bf(x.x); u.us[1] = f2bf(x.y); u.us[2] = f2bf(x.z); u.us[3] = f2bf(x.w);
        u.us[4] = f2bf(y.x); u.us[5] = f2bf(y.y); u.us[6] = f2bf(y.z); u.us[7] = f2bf(y.w);
        af[kc] = u.v;
    }

    float dv = dinv1[node];
    #pragma unroll
    for (int ct = 0; ct < 4; ++ct) {
        floatx4 acc = {0.f, 0.f, 0.f, 0.f};
        acc = __builtin_amdgcn_mfma_f32_16x16x32_bf16(wf[ct * 4 + 0], af[0], acc, 0, 0, 0);
        acc = __builtin_amdgcn_mfma_f32_16x16x32_bf16(wf[ct * 4 + 1], af[1], acc, 0, 0, 0);
        acc = __builtin_amdgcn_mfma_f32_16x16x32_bf16(wf[ct * 4 + 2], af[2], acc, 0, 0, 0);
        acc = __builtin_amdgcn_mfma_f32_16x16x32_bf16(wf[ct * 4 + 3], af[3], acc, 0, 0, 0);
        uint2 o;
        o.x = pk2(acc[0] * dv, acc[1] * dv);
        o.y = pk2(acc[2] * dv, acc[3] * dv);
        *reinterpret_cast<uint2*>(Xs + (size_t)node * H_F + ct * 16 + lk * 4) = o;
    }
}

// ---------------- prop1: 4 edge-groups x 16 lanes, uint2 gathers ----------------
// h1[d] = dinv1[d]*(sum Xs[s] + Xs[d]);  h1s[d] = h1[d]*dinv2[d]
__global__ __launch_bounds__(256) void prop1_kernel(const int* __restrict__ offsets,
                                                    const int* __restrict__ sorted_src,
                                                    const unsigned short* __restrict__ Xs,
                                                    const float* __restrict__ dinv1,
                                                    const float* __restrict__ dinv2,
                                                    unsigned short* __restrict__ h1,
                                                    unsigned short* __restrict__ h1s, int N) {
    int wid  = (blockIdx.x * blockDim.x + threadIdx.x) >> 6;
    int lane = threadIdx.x & 63;
    if (wid >= N) return;
    int d = wid;
    int g = lane >> 4, fl = lane & 15;

    int beg = offsets[d], end = offsets[d + 1];
    float c0 = 0.f, c1 = 0.f, c2 = 0.f, c3 = 0.f;

    int i0 = beg;
    for (; i0 + 64 <= end; i0 += 64) {
        int s_l = sorted_src[i0 + lane];
        #pragma unroll
        for (int j = 0; j < 64; j += 4) {
            int s = __shfl(s_l, j + g);
            uint2 v = *reinterpret_cast<const uint2*>(Xs + ((size_t)s << 6) + (fl << 2));
            c0 += bflo(v.x); c1 += bfhi(v.x); c2 += bflo(v.y); c3 += bfhi(v.y);
        }
    }
    int rem = end - i0;
    if (rem > 0) {
        int s_l = (i0 + lane < end) ? sorted_src[i0 + lane] : ZROW;
        for (int j = 0; j < rem; j += 4) {
            int s = __shfl(s_l, j + g);     // slots >= rem hit the zero row
            uint2 v = *reinterpret_cast<const uint2*>(Xs + ((size_t)s << 6) + (fl << 2));
            c0 += bflo(v.x); c1 += bfhi(v.x); c2 += bflo(v.y); c3 += bfhi(v.y);
        }
    }
    // cross-group reduce (4 groups)
    c0 += __shfl_xor(c0, 16); c1 += __shfl_xor(c1, 16);
    c2 += __shfl_xor(c2, 16); c3 += __shfl_xor(c3, 16);
    c0 += __shfl_xor(c0, 32); c1 += __shfl_xor(c1, 32);
    c2 += __shfl_xor(c2, 32); c3 += __shfl_xor(c3, 32);

    float dv  = dinv1[d];
    float dv2 = dinv2[d];
    uint2 sv = *reinterpret_cast<const uint2*>(Xs + ((size_t)d << 6) + (fl << 2));
    float h0 = dv * (c0 + bflo(sv.x));
    float h1v = dv * (c1 + bfhi(sv.x));
    float h2 = dv * (c2 + bflo(sv.y));
    float h3 = dv * (c3 + bfhi(sv.y));
    if (g == 0) {
        uint2 o1; o1.x = pk2(h0, h1v); o1.y = pk2(h2, h3);
        *reinterpret_cast<uint2*>(h1 + ((size_t)d << 6) + (fl << 2)) = o1;
        uint2 o2; o2.x = pk2(h0 * dv2, h1v * dv2); o2.y = pk2(h2 * dv2, h3 * dv2);
        *reinterpret_cast<uint2*>(h1s + ((size_t)d << 6) + (fl << 2)) = o2;
    }
}

// ---------------- prop2: gather h1s + alpha combine ----------------
// out[d] = a0*h1[d] + a1*dinv2[d]*sum(h1s[s])
__global__ __launch_bounds__(256) void prop2_kernel(const int* __restrict__ offsets,
                                                    const int* __restrict__ sorted_src,
                                                    const unsigned short* __restrict__ h1,
                                                    const unsigned short* __restrict__ h1s,
                                                    const float* __restrict__ dinv2,
                                                    const float* __restrict__ alphas,
                                                    float* __restrict__ out, int N) {
    int wid  = (blockIdx.x * blockDim.x + threadIdx.x) >> 6;
    int lane = threadIdx.x & 63;
    if (wid >= N) return;
    int d = wid;
    int g = lane >> 4, fl = lane & 15;

    float e0 = expf(alphas[0]), e1 = expf(alphas[1]);
    float aw0 = e0 / (e0 + e1), aw1 = e1 / (e0 + e1);

    int beg = offsets[d], end = offsets[d + 1];
    float c0 = 0.f, c1 = 0.f, c2 = 0.f, c3 = 0.f;

    int i0 = beg;
    for (; i0 + 64 <= end; i0 += 64) {
        int s_l = sorted_src[i0 + lane];
        #pragma unroll
        for (int j = 0; j < 64; j += 4) {
            int s = __shfl(s_l, j + g);
            uint2 v = *reinterpret_cast<const uint2*>(h1s + ((size_t)s << 6) + (fl << 2));
            c0 += bflo(v.x); c1 += bfhi(v.x); c2 += bflo(v.y); c3 += bfhi(v.y);
        }
    }
    int rem = end - i0;
    if (rem > 0) {
        int s_l = (i0 + lane < end) ? sorted_src[i0 + lane] : ZROW;
        for (int j = 0; j < rem; j += 4) {
            int s = __shfl(s_l, j + g);
            uint2 v = *reinterpret_cast<const uint2*>(h1s + ((size_t)s << 6) + (fl << 2));
            c0 += bflo(v.x); c1 += bfhi(v.x); c2 += bflo(v.y); c3 += bfhi(v.y);
        }
    }
    c0 += __shfl_xor(c0, 16); c1 += __shfl_xor(c1, 16);
    c2 += __shfl_xor(c2, 16); c3 += __shfl_xor(c3, 16);
    c0 += __shfl_xor(c0, 32); c1 += __shfl_xor(c1, 32);
    c2 += __shfl_xor(c2, 32); c3 += __shfl_xor(c3, 32);

    if (g == 0) {
        float sa1 = aw1 * dinv2[d];
        uint2 sv = *reinterpret_cast<const uint2*>(h1 + ((size_t)d << 6) + (fl << 2));
        float4 o;
        o.x = aw0 * bflo(sv.x) + sa1 * c0;
        o.y = aw0 * bfhi(sv.x) + sa1 * c1;
        o.z = aw0 * bflo(sv.y) + sa1 * c2;
        o.w = aw0 * bfhi(sv.y) + sa1 * c3;
        *reinterpret_cast<float4*>(out + ((size_t)d << 6) + (fl << 2)) = o;
    }
}

extern "C" void kernel_launch(void* const* d_in, const int* in_sizes, int n_in,
                              void* d_out, int out_size, void* d_ws, size_t ws_size,
                              hipStream_t stream) {
    const int*   edge_index = (const int*)d_in[0];   // [2, E]
    const float* in_feat    = (const float*)d_in[1]; // [N, 128]
    const float* W1         = (const float*)d_in[2]; // [128, 64]
    const float* alphas     = (const float*)d_in[3]; // [2]
    float*       out        = (float*)d_out;         // [N, 64]

    const int* src = edge_index;
    const int* dst = edge_index + N_EDGES;

    // workspace layout (bf16 tables: (N+16) rows of 64 bf16; row N = zero sentinel)
    char* ws = (char*)d_ws;
    size_t tabBytes = (size_t)(N_NODES + 16) * H_F * 2;
    unsigned short* Xs  = (unsigned short*)(ws);                 // 12.8 MB
    unsigned int*   tmp = (unsigned int*)(ws);                   // 6.4 MB — aliases Xs (dead until gemm)
    unsigned short* h1  = (unsigned short*)(ws + tabBytes);      // 12.8 MB
    unsigned short* h1s = (unsigned short*)(ws + 2 * tabBytes);  // 12.8 MB
    char* p = ws + 3 * tabBytes;
    int*   sorted = (int*)p;   p += (size_t)N_EDGES * 4;         // 6.4 MB
    int*   offs   = (int*)p;   p += (size_t)(N_NODES + 4) * 4;
    float* dinv1  = (float*)p; p += (size_t)N_NODES * 4;
    float* dinv2  = (float*)p; p += (size_t)N_NODES * 4;
    int*   ccnt   = (int*)p;   p += (size_t)NBKT * 4;
    int*   cofs   = (int*)p;   p += (size_t)(NBKT + 1) * 4;
    int*   ccur   = (int*)p;   p += (size_t)NBKT * 4;
    unsigned int* wfrag = (unsigned int*)p; p += 8192 * 4;       // 32 KB packed W frags

    hipMemsetAsync(ccnt, 0, (size_t)NBKT * sizeof(int), stream);
    // zero sentinel rows (row index N) for the two gather tables
    hipMemsetAsync(Xs  + (size_t)N_NODES * H_F, 0, H_F * 2, stream);
    hipMemsetAsync(h1s + (size_t)N_NODES * H_F, 0, H_F * 2, stream);

    wpack_kernel<<<32, 256, 0, stream>>>(W1, wfrag);
    hist_kernel<<<512, 256, 0, stream>>>(dst, ccnt, N_EDGES);
    scan_coarse_kernel<<<1, 64, 0, stream>>>(ccnt, cofs, ccur, offs, N_EDGES);
    coarse_scatter_kernel<<<(N_EDGES + EPB - 1) / EPB, 256, 0, stream>>>(src, dst, ccur, tmp, N_EDGES);
    bucket_kernel<<<NBKT, 512, 0, stream>>>(tmp, cofs, offs, sorted, dinv1, dinv2, N_NODES);

    // gemm after bucket_kernel (tmp aliases Xs; needs dinv1)
    int nTiles = N_NODES / 16;                        // 6250
    gemm_kernel<<<(nTiles + 3) / 4, 256, 0, stream>>>(in_feat, (const uint4*)wfrag, dinv1, Xs, nTiles);

    int nblocks = (N_NODES * 64 + 255) / 256; // one wave per node
    prop1_kernel<<<nblocks, 256, 0, stream>>>(offs, sorted, Xs, dinv1, dinv2, h1, h1s, N_NODES);
    prop2_kernel<<<nblocks, 256, 0, stream>>>(offs, sorted, h1, h1s, dinv2, alphas, out, N_NODES);
}

// Round 8
// 174.964 us; speedup vs baseline: 1.1680x; 1.1680x over previous
//
#include <hip/hip_runtime.h>

#define N_NODES 100000
#define N_EDGES 1600000
#define IN_F 128
#define H_F 64
#define ZROW N_NODES    // zero sentinel row index in gather tables

#define BSH 10          // coarse bucket = dst >> 10
#define BNODES 1024     // nodes per bucket
#define NBKT 98         // ceil(100000 / 1024)
#define EPB 4096        // edges per block in coarse scatter

typedef short short8 __attribute__((ext_vector_type(8)));
typedef float floatx4 __attribute__((ext_vector_type(4)));

union U16x8 { short8 v; unsigned short us[8]; unsigned int u[4]; };

// ---- bf16 helpers ----
static __device__ __forceinline__ unsigned short f2bf(float f) {
    unsigned int u = __float_as_uint(f);
    unsigned int r = (u + 0x7FFFu + ((u >> 16) & 1u)) >> 16;
    return (unsigned short)r;
}
static __device__ __forceinline__ float bf2f(unsigned short v) {
    return __uint_as_float(((unsigned int)v) << 16);
}
static __device__ __forceinline__ float bflo(unsigned int u) {
    return __uint_as_float(u << 16);
}
static __device__ __forceinline__ float bfhi(unsigned int u) {
    return __uint_as_float(u & 0xFFFF0000u);
}
static __device__ __forceinline__ unsigned int pk2(float a, float b) {
    return (unsigned int)f2bf(a) | ((unsigned int)f2bf(b) << 16);
}

// ---------------- W fragment pre-pack ----------------
__global__ __launch_bounds__(256) void wpack_kernel(const float* __restrict__ W,
                                                    unsigned int* __restrict__ wfrag) {
    int i = blockIdx.x * 256 + threadIdx.x;   // [0, 8192)
    int reg = i & 3, lane = (i >> 2) & 63, fkc = i >> 8;
    int ct = fkc >> 2, kc = fkc & 3;
    int fcol = ct * 16 + (lane & 15);
    int k = kc * 32 + (lane >> 4) * 8 + reg * 2;
    wfrag[i] = pk2(W[k * 64 + fcol], W[(k + 1) * 64 + fcol]);
}

// ---------------- coarse histogram ----------------
__global__ __launch_bounds__(256) void hist_kernel(const int* __restrict__ dst,
                                                   int* __restrict__ ccnt, int E) {
    __shared__ int lh[4 * NBKT];
    int w = threadIdx.x >> 6;
    for (int i = threadIdx.x; i < 4 * NBKT; i += 256) lh[i] = 0;
    __syncthreads();
    int stride = gridDim.x * blockDim.x;
    for (int i = blockIdx.x * blockDim.x + threadIdx.x; i < E; i += stride)
        atomicAdd(&lh[w * NBKT + (dst[i] >> BSH)], 1);
    __syncthreads();
    for (int b = threadIdx.x; b < NBKT; b += 256) {
        int s = lh[b] + lh[NBKT + b] + lh[2 * NBKT + b] + lh[3 * NBKT + b];
        if (s) atomicAdd(&ccnt[b], s);
    }
}

// ---------------- coarse offsets + sentinel ----------------
__global__ void scan_coarse_kernel(const int* __restrict__ ccnt,
                                   int* __restrict__ cofs, int* __restrict__ ccur,
                                   int* __restrict__ offsets, int E) {
    if (threadIdx.x == 0) {
        int run = 0;
        for (int b = 0; b < NBKT; ++b) { cofs[b] = run; ccur[b] = run; run += ccnt[b]; }
        cofs[NBKT] = run;              // == E
        offsets[N_NODES] = E;          // sentinel for prop kernels
    }
}

// ---------------- pass 1: coarse scatter, packed (local_dst<<17 | src) ----------------
__global__ __launch_bounds__(256) void coarse_scatter_kernel(const int* __restrict__ src,
                                                             const int* __restrict__ dst,
                                                             int* __restrict__ ccur,
                                                             unsigned int* __restrict__ tmp, int E) {
    __shared__ unsigned int buf[EPB];               // 16 KB
    __shared__ unsigned char bktA[EPB];             // 4 KB
    __shared__ int cnt[NBKT], lofs[NBKT], gofs[NBKT];
    int base = blockIdx.x * EPB;
    int n = E - base; if (n > EPB) n = EPB;

    for (int i = threadIdx.x; i < NBKT; i += 256) cnt[i] = 0;
    __syncthreads();

    unsigned int v[16]; int bk[16], loc[16];
    #pragma unroll
    for (int j = 0; j < 16; ++j) {
        int o = threadIdx.x + j * 256;
        bk[j] = -1;
        if (o < n) {
            int s = src[base + o];
            int d = dst[base + o];
            bk[j]  = d >> BSH;
            v[j]   = ((unsigned int)(d & (BNODES - 1)) << 17) | (unsigned int)s;
            loc[j] = atomicAdd(&cnt[bk[j]], 1);
        }
    }
    __syncthreads();
    if (threadIdx.x == 0) {
        int run = 0;
        for (int b = 0; b < NBKT; ++b) { lofs[b] = run; run += cnt[b]; }
    }
    __syncthreads();
    if (threadIdx.x < NBKT && cnt[threadIdx.x] > 0)
        gofs[threadIdx.x] = atomicAdd(&ccur[threadIdx.x], cnt[threadIdx.x]);
    __syncthreads();
    #pragma unroll
    for (int j = 0; j < 16; ++j)
        if (bk[j] >= 0) {
            int p = lofs[bk[j]] + loc[j];
            buf[p]  = v[j];
            bktA[p] = (unsigned char)bk[j];
        }
    __syncthreads();
    for (int i = threadIdx.x; i < n; i += 256) {
        int b = bktA[i];
        tmp[gofs[b] + (i - lofs[b])] = buf[i];
    }
}

// ---------------- pass 2: per-bucket LDS pipeline ----------------
__global__ __launch_bounds__(512) void bucket_kernel(const unsigned int* __restrict__ tmp,
                                                     const int* __restrict__ cofs,
                                                     int* __restrict__ offsets,
                                                     int* __restrict__ sorted_src,
                                                     float* __restrict__ dinv1,
                                                     float* __restrict__ dinv2, int N) {
    __shared__ int cnt[BNODES];
    __shared__ int sd[512];
    int b   = blockIdx.x;
    int tid = threadIdx.x;
    int beg = cofs[b], end = cofs[b + 1];

    for (int i = tid; i < BNODES; i += 512) cnt[i] = 0;
    __syncthreads();
    for (int i = beg + tid; i < end; i += 512)
        atomicAdd(&cnt[tmp[i] >> 17], 1);
    __syncthreads();

    int c0 = cnt[2 * tid], c1 = cnt[2 * tid + 1];
    int s  = c0 + c1;
    sd[tid] = s;
    __syncthreads();
    for (int off = 1; off < 512; off <<= 1) {
        int t = (tid >= off) ? sd[tid - off] : 0;
        __syncthreads();
        sd[tid] += t;
        __syncthreads();
    }
    int ex = sd[tid] - s;
    int g0 = beg + ex, g1 = beg + ex + c0;

    int node0 = b * BNODES + 2 * tid;
    if (node0 < N) {
        offsets[node0] = g0;
        dinv1[node0] = rsqrtf((float)(c0 + 1));
        dinv2[node0] = c0 ? rsqrtf((float)c0) : 0.0f;
    }
    if (node0 + 1 < N) {
        offsets[node0 + 1] = g1;
        dinv1[node0 + 1] = rsqrtf((float)(c1 + 1));
        dinv2[node0 + 1] = c1 ? rsqrtf((float)c1) : 0.0f;
    }
    __syncthreads();
    cnt[2 * tid] = g0;
    cnt[2 * tid + 1] = g1;
    __syncthreads();

    for (int i = beg + tid; i < end; i += 512) {
        unsigned int v = tmp[i];
        int p = atomicAdd(&cnt[v >> 17], 1);
        sorted_src[p] = (int)(v & 0x1FFFFu);
    }
}

// ---------------- MFMA GEMM: Xs = bf16((in_feat @ W1) * dinv1) ----------------
__global__ __launch_bounds__(256) void gemm_kernel(const float* __restrict__ A,
                                                   const uint4* __restrict__ wfrag,
                                                   const float* __restrict__ dinv1,
                                                   unsigned short* __restrict__ Xs, int nTiles) {
    int wid = blockIdx.x * 4 + (threadIdx.x >> 6);
    if (wid >= nTiles) return;
    int lane = threadIdx.x & 63;
    int lrow = lane & 15, lk = lane >> 4;

    short8 wf[16];
    #pragma unroll
    for (int i = 0; i < 16; ++i)
        wf[i] = *reinterpret_cast<const short8*>(&wfrag[i * 64 + lane]);

    int node = wid * 16 + lrow;
    const float4* ap = reinterpret_cast<const float4*>(A + (size_t)node * IN_F);

    short8 af[4];
    #pragma unroll
    for (int kc = 0; kc < 4; ++kc) {
        float4 x = ap[kc * 8 + lk * 2];
        float4 y = ap[kc * 8 + lk * 2 + 1];
        U16x8 u;
        u.us[0] = f2bf(x.x); u.us[1] = f2bf(x.y); u.us[2] = f2bf(x.z); u.us[3] = f2bf(x.w);
        u.us[4] = f2bf(y.x); u.us[5] = f2bf(y.y); u.us[6] = f2bf(y.z); u.us[7] = f2bf(y.w);
        af[kc] = u.v;
    }

    float dv = dinv1[node];
    #pragma unroll
    for (int ct = 0; ct < 4; ++ct) {
        floatx4 acc = {0.f, 0.f, 0.f, 0.f};
        acc = __builtin_amdgcn_mfma_f32_16x16x32_bf16(wf[ct * 4 + 0], af[0], acc, 0, 0, 0);
        acc = __builtin_amdgcn_mfma_f32_16x16x32_bf16(wf[ct * 4 + 1], af[1], acc, 0, 0, 0);
        acc = __builtin_amdgcn_mfma_f32_16x16x32_bf16(wf[ct * 4 + 2], af[2], acc, 0, 0, 0);
        acc = __builtin_amdgcn_mfma_f32_16x16x32_bf16(wf[ct * 4 + 3], af[3], acc, 0, 0, 0);
        uint2 o;
        o.x = pk2(acc[0] * dv, acc[1] * dv);
        o.y = pk2(acc[2] * dv, acc[3] * dv);
        *reinterpret_cast<uint2*>(Xs + (size_t)node * H_F + ct * 16 + lk * 4) = o;
    }
}

// ---------------- prop1: batches of 16 edges, 4 gathers in flight per lane ----------------
// h1[d] = dinv1[d]*(sum Xs[s] + Xs[d]);  h1s[d] = h1[d]*dinv2[d]
__global__ __launch_bounds__(256) void prop1_kernel(const int* __restrict__ offsets,
                                                    const int* __restrict__ sorted_src,
                                                    const unsigned short* __restrict__ Xs,
                                                    const float* __restrict__ dinv1,
                                                    const float* __restrict__ dinv2,
                                                    unsigned short* __restrict__ h1,
                                                    unsigned short* __restrict__ h1s, int N) {
    int wid  = (blockIdx.x * blockDim.x + threadIdx.x) >> 6;
    int lane = threadIdx.x & 63;
    if (wid >= N) return;
    int d = wid;
    int g = lane >> 4, fl = lane & 15;

    int beg = offsets[d], end = offsets[d + 1];
    float c0 = 0.f, c1 = 0.f, c2 = 0.f, c3 = 0.f;

    for (int i0 = beg; i0 < end; i0 += 64) {
        int lim = end - i0;                     // edges in this chunk (>0)
        int s_l = (lane < lim) ? sorted_src[i0 + lane] : ZROW;
        int nE  = lim > 64 ? 64 : lim;
        int nb  = (nE + 15) >> 4;               // batches of 16
        for (int b = 0; b < nb; ++b) {
            int j0 = b * 16 + g;
            // issue all 4 gathers before accumulating (sentinel rows are zero)
            int s0 = __shfl(s_l, j0 + 0), s1 = __shfl(s_l, j0 + 4);
            int s2 = __shfl(s_l, j0 + 8), s3 = __shfl(s_l, j0 + 12);
            uint2 v0 = *reinterpret_cast<const uint2*>(Xs + ((size_t)s0 << 6) + (fl << 2));
            uint2 v1 = *reinterpret_cast<const uint2*>(Xs + ((size_t)s1 << 6) + (fl << 2));
            uint2 v2 = *reinterpret_cast<const uint2*>(Xs + ((size_t)s2 << 6) + (fl << 2));
            uint2 v3 = *reinterpret_cast<const uint2*>(Xs + ((size_t)s3 << 6) + (fl << 2));
            c0 += bflo(v0.x); c1 += bfhi(v0.x); c2 += bflo(v0.y); c3 += bfhi(v0.y);
            c0 += bflo(v1.x); c1 += bfhi(v1.x); c2 += bflo(v1.y); c3 += bfhi(v1.y);
            c0 += bflo(v2.x); c1 += bfhi(v2.x); c2 += bflo(v2.y); c3 += bfhi(v2.y);
            c0 += bflo(v3.x); c1 += bfhi(v3.x); c2 += bflo(v3.y); c3 += bfhi(v3.y);
        }
    }
    // cross-group reduce (4 groups)
    c0 += __shfl_xor(c0, 16); c1 += __shfl_xor(c1, 16);
    c2 += __shfl_xor(c2, 16); c3 += __shfl_xor(c3, 16);
    c0 += __shfl_xor(c0, 32); c1 += __shfl_xor(c1, 32);
    c2 += __shfl_xor(c2, 32); c3 += __shfl_xor(c3, 32);

    float dv  = dinv1[d];
    float dv2 = dinv2[d];
    uint2 sv = *reinterpret_cast<const uint2*>(Xs + ((size_t)d << 6) + (fl << 2));
    float h0  = dv * (c0 + bflo(sv.x));
    float h1v = dv * (c1 + bfhi(sv.x));
    float h2  = dv * (c2 + bflo(sv.y));
    float h3  = dv * (c3 + bfhi(sv.y));
    if (g == 0) {
        uint2 o1; o1.x = pk2(h0, h1v); o1.y = pk2(h2, h3);
        *reinterpret_cast<uint2*>(h1 + ((size_t)d << 6) + (fl << 2)) = o1;
        uint2 o2; o2.x = pk2(h0 * dv2, h1v * dv2); o2.y = pk2(h2 * dv2, h3 * dv2);
        *reinterpret_cast<uint2*>(h1s + ((size_t)d << 6) + (fl << 2)) = o2;
    }
}

// ---------------- prop2: gather h1s + alpha combine ----------------
// out[d] = a0*h1[d] + a1*dinv2[d]*sum(h1s[s])
__global__ __launch_bounds__(256) void prop2_kernel(const int* __restrict__ offsets,
                                                    const int* __restrict__ sorted_src,
                                                    const unsigned short* __restrict__ h1,
                                                    const unsigned short* __restrict__ h1s,
                                                    const float* __restrict__ dinv2,
                                                    const float* __restrict__ alphas,
                                                    float* __restrict__ out, int N) {
    int wid  = (blockIdx.x * blockDim.x + threadIdx.x) >> 6;
    int lane = threadIdx.x & 63;
    if (wid >= N) return;
    int d = wid;
    int g = lane >> 4, fl = lane & 15;

    float e0 = expf(alphas[0]), e1 = expf(alphas[1]);
    float aw0 = e0 / (e0 + e1), aw1 = e1 / (e0 + e1);

    int beg = offsets[d], end = offsets[d + 1];
    float c0 = 0.f, c1 = 0.f, c2 = 0.f, c3 = 0.f;

    for (int i0 = beg; i0 < end; i0 += 64) {
        int lim = end - i0;
        int s_l = (lane < lim) ? sorted_src[i0 + lane] : ZROW;
        int nE  = lim > 64 ? 64 : lim;
        int nb  = (nE + 15) >> 4;
        for (int b = 0; b < nb; ++b) {
            int j0 = b * 16 + g;
            int s0 = __shfl(s_l, j0 + 0), s1 = __shfl(s_l, j0 + 4);
            int s2 = __shfl(s_l, j0 + 8), s3 = __shfl(s_l, j0 + 12);
            uint2 v0 = *reinterpret_cast<const uint2*>(h1s + ((size_t)s0 << 6) + (fl << 2));
            uint2 v1 = *reinterpret_cast<const uint2*>(h1s + ((size_t)s1 << 6) + (fl << 2));
            uint2 v2 = *reinterpret_cast<const uint2*>(h1s + ((size_t)s2 << 6) + (fl << 2));
            uint2 v3 = *reinterpret_cast<const uint2*>(h1s + ((size_t)s3 << 6) + (fl << 2));
            c0 += bflo(v0.x); c1 += bfhi(v0.x); c2 += bflo(v0.y); c3 += bfhi(v0.y);
            c0 += bflo(v1.x); c1 += bfhi(v1.x); c2 += bflo(v1.y); c3 += bfhi(v1.y);
            c0 += bflo(v2.x); c1 += bfhi(v2.x); c2 += bflo(v2.y); c3 += bfhi(v2.y);
            c0 += bflo(v3.x); c1 += bfhi(v3.x); c2 += bflo(v3.y); c3 += bfhi(v3.y);
        }
    }
    c0 += __shfl_xor(c0, 16); c1 += __shfl_xor(c1, 16);
    c2 += __shfl_xor(c2, 16); c3 += __shfl_xor(c3, 16);
    c0 += __shfl_xor(c0, 32); c1 += __shfl_xor(c1, 32);
    c2 += __shfl_xor(c2, 32); c3 += __shfl_xor(c3, 32);

    if (g == 0) {
        float sa1 = aw1 * dinv2[d];
        uint2 sv = *reinterpret_cast<const uint2*>(h1 + ((size_t)d << 6) + (fl << 2));
        float4 o;
        o.x = aw0 * bflo(sv.x) + sa1 * c0;
        o.y = aw0 * bfhi(sv.x) + sa1 * c1;
        o.z = aw0 * bflo(sv.y) + sa1 * c2;
        o.w = aw0 * bfhi(sv.y) + sa1 * c3;
        *reinterpret_cast<float4*>(out + ((size_t)d << 6) + (fl << 2)) = o;
    }
}

extern "C" void kernel_launch(void* const* d_in, const int* in_sizes, int n_in,
                              void* d_out, int out_size, void* d_ws, size_t ws_size,
                              hipStream_t stream) {
    const int*   edge_index = (const int*)d_in[0];   // [2, E]
    const float* in_feat    = (const float*)d_in[1]; // [N, 128]
    const float* W1         = (const float*)d_in[2]; // [128, 64]
    const float* alphas     = (const float*)d_in[3]; // [2]
    float*       out        = (float*)d_out;         // [N, 64]

    const int* src = edge_index;
    const int* dst = edge_index + N_EDGES;

    // workspace layout (bf16 tables: (N+16) rows of 64 bf16; row N = zero sentinel)
    char* ws = (char*)d_ws;
    size_t tabBytes = (size_t)(N_NODES + 16) * H_F * 2;
    unsigned short* Xs  = (unsigned short*)(ws);                 // 12.8 MB
    unsigned int*   tmp = (unsigned int*)(ws);                   // 6.4 MB — aliases Xs (dead until gemm)
    unsigned short* h1  = (unsigned short*)(ws + tabBytes);      // 12.8 MB
    unsigned short* h1s = (unsigned short*)(ws + 2 * tabBytes);  // 12.8 MB
    char* p = ws + 3 * tabBytes;
    int*   sorted = (int*)p;   p += (size_t)N_EDGES * 4;         // 6.4 MB
    int*   offs   = (int*)p;   p += (size_t)(N_NODES + 4) * 4;
    float* dinv1  = (float*)p; p += (size_t)N_NODES * 4;
    float* dinv2  = (float*)p; p += (size_t)N_NODES * 4;
    int*   ccnt   = (int*)p;   p += (size_t)NBKT * 4;
    int*   cofs   = (int*)p;   p += (size_t)(NBKT + 1) * 4;
    int*   ccur   = (int*)p;   p += (size_t)NBKT * 4;
    unsigned int* wfrag = (unsigned int*)p; p += 8192 * 4;       // 32 KB packed W frags

    hipMemsetAsync(ccnt, 0, (size_t)NBKT * sizeof(int), stream);
    // zero sentinel rows (row index N) for the two gather tables
    hipMemsetAsync(Xs  + (size_t)N_NODES * H_F, 0, H_F * 2, stream);
    hipMemsetAsync(h1s + (size_t)N_NODES * H_F, 0, H_F * 2, stream);

    wpack_kernel<<<32, 256, 0, stream>>>(W1, wfrag);
    hist_kernel<<<512, 256, 0, stream>>>(dst, ccnt, N_EDGES);
    scan_coarse_kernel<<<1, 64, 0, stream>>>(ccnt, cofs, ccur, offs, N_EDGES);
    coarse_scatter_kernel<<<(N_EDGES + EPB - 1) / EPB, 256, 0, stream>>>(src, dst, ccur, tmp, N_EDGES);
    bucket_kernel<<<NBKT, 512, 0, stream>>>(tmp, cofs, offs, sorted, dinv1, dinv2, N_NODES);

    // gemm after bucket_kernel (tmp aliases Xs; needs dinv1)
    int nTiles = N_NODES / 16;                        // 6250
    gemm_kernel<<<(nTiles + 3) / 4, 256, 0, stream>>>(in_feat, (const uint4*)wfrag, dinv1, Xs, nTiles);

    int nblocks = (N_NODES * 64 + 255) / 256; // one wave per node
    prop1_kernel<<<nblocks, 256, 0, stream>>>(offs, sorted, Xs, dinv1, dinv2, h1, h1s, N_NODES);
    prop2_kernel<<<nblocks, 256, 0, stream>>>(offs, sorted, h1, h1s, dinv2, alphas, out, N_NODES);
}

// Round 9
// 139.695 us; speedup vs baseline: 1.4629x; 1.2525x over previous
//
#include <hip/hip_runtime.h>

#define N_NODES 100000
#define N_EDGES 1600000
#define IN_F 128
#define H_F 64
#define ZROW N_NODES    // zero sentinel row index in gather tables

#define BSH 10          // coarse bucket = dst >> 10
#define BNODES 1024     // nodes per bucket
#define NBKT 98         // ceil(100000 / 1024)
#define EPB 4096        // edges per block in coarse scatter
#define BCAP 20000      // slack capacity per coarse bucket in tmp (mean 16327, +29 sigma)

typedef short short8 __attribute__((ext_vector_type(8)));
typedef float floatx4 __attribute__((ext_vector_type(4)));

union U16x8 { short8 v; unsigned short us[8]; unsigned int u[4]; };

// ---- bf16 helpers ----
static __device__ __forceinline__ unsigned short f2bf(float f) {
    unsigned int u = __float_as_uint(f);
    unsigned int r = (u + 0x7FFFu + ((u >> 16) & 1u)) >> 16;
    return (unsigned short)r;
}
static __device__ __forceinline__ float bf2f(unsigned short v) {
    return __uint_as_float(((unsigned int)v) << 16);
}
static __device__ __forceinline__ float bflo(unsigned int u) {
    return __uint_as_float(u << 16);
}
static __device__ __forceinline__ float bfhi(unsigned int u) {
    return __uint_as_float(u & 0xFFFF0000u);
}
static __device__ __forceinline__ unsigned int pk2(float a, float b) {
    return (unsigned int)f2bf(a) | ((unsigned int)f2bf(b) << 16);
}

// ---------------- init: slack cursors + prop sentinel ----------------
__global__ void init_kernel(int* __restrict__ ccur, int* __restrict__ offsets) {
    int i = threadIdx.x;
    if (i < NBKT) ccur[i] = i * BCAP;
    if (i == 0) offsets[N_NODES] = N_EDGES;
}

// ---------------- W fragment pre-pack ----------------
__global__ __launch_bounds__(256) void wpack_kernel(const float* __restrict__ W,
                                                    unsigned int* __restrict__ wfrag) {
    int i = blockIdx.x * 256 + threadIdx.x;   // [0, 8192)
    int reg = i & 3, lane = (i >> 2) & 63, fkc = i >> 8;
    int ct = fkc >> 2, kc = fkc & 3;
    int fcol = ct * 16 + (lane & 15);
    int k = kc * 32 + (lane >> 4) * 8 + reg * 2;
    wfrag[i] = pk2(W[k * 64 + fcol], W[(k + 1) * 64 + fcol]);
}

// ---------------- pass 1: coarse scatter into slack buckets ----------------
__global__ __launch_bounds__(256) void coarse_scatter_kernel(const int* __restrict__ src,
                                                             const int* __restrict__ dst,
                                                             int* __restrict__ ccur,
                                                             unsigned int* __restrict__ tmp, int E) {
    __shared__ unsigned int buf[EPB];               // 16 KB
    __shared__ unsigned char bktA[EPB];             // 4 KB
    __shared__ int cnt[NBKT], lofs[NBKT], gofs[NBKT];
    int base = blockIdx.x * EPB;
    int n = E - base; if (n > EPB) n = EPB;

    for (int i = threadIdx.x; i < NBKT; i += 256) cnt[i] = 0;
    __syncthreads();

    unsigned int v[16]; int bk[16], loc[16];
    #pragma unroll
    for (int j = 0; j < 16; ++j) {
        int o = threadIdx.x + j * 256;
        bk[j] = -1;
        if (o < n) {
            int s = src[base + o];
            int d = dst[base + o];
            bk[j]  = d >> BSH;
            v[j]   = ((unsigned int)(d & (BNODES - 1)) << 17) | (unsigned int)s;
            loc[j] = atomicAdd(&cnt[bk[j]], 1);
        }
    }
    __syncthreads();
    if (threadIdx.x == 0) {
        int run = 0;
        for (int b = 0; b < NBKT; ++b) { lofs[b] = run; run += cnt[b]; }
    }
    __syncthreads();
    if (threadIdx.x < NBKT && cnt[threadIdx.x] > 0)
        gofs[threadIdx.x] = atomicAdd(&ccur[threadIdx.x], cnt[threadIdx.x]);
    __syncthreads();
    #pragma unroll
    for (int j = 0; j < 16; ++j)
        if (bk[j] >= 0) {
            int p = lofs[bk[j]] + loc[j];
            buf[p]  = v[j];
            bktA[p] = (unsigned char)bk[j];
        }
    __syncthreads();
    for (int i = threadIdx.x; i < n; i += 256) {
        int b = bktA[i];
        tmp[gofs[b] + (i - lofs[b])] = buf[i];
    }
}

// ---------------- scan over 98 bucket counts -> contiguous output bases ----------------
__global__ void scan98_kernel(const int* __restrict__ ccur, int* __restrict__ cofs) {
    if (threadIdx.x == 0) {
        int run = 0;
        for (int b = 0; b < NBKT; ++b) {
            cofs[b] = run;
            run += ccur[b] - b * BCAP;   // count in bucket b
        }
        cofs[NBKT] = run;                // == E
    }
}

// ---------------- pass 2: per-bucket LDS pipeline ----------------
__global__ __launch_bounds__(512) void bucket_kernel(const unsigned int* __restrict__ tmp,
                                                     const int* __restrict__ ccur,
                                                     const int* __restrict__ cofs,
                                                     int* __restrict__ offsets,
                                                     int* __restrict__ sorted_src,
                                                     float* __restrict__ dinv1,
                                                     float* __restrict__ dinv2, int N) {
    __shared__ int cnt[BNODES];
    __shared__ int sd[512];
    int b   = blockIdx.x;
    int tid = threadIdx.x;
    int tbeg = b * BCAP, tend = ccur[b];   // bucket's run in tmp (slack layout)
    int obase = cofs[b];                   // contiguous base in sorted_src

    for (int i = tid; i < BNODES; i += 512) cnt[i] = 0;
    __syncthreads();
    for (int i = tbeg + tid; i < tend; i += 512)
        atomicAdd(&cnt[tmp[i] >> 17], 1);
    __syncthreads();

    int c0 = cnt[2 * tid], c1 = cnt[2 * tid + 1];
    int s  = c0 + c1;
    sd[tid] = s;
    __syncthreads();
    for (int off = 1; off < 512; off <<= 1) {
        int t = (tid >= off) ? sd[tid - off] : 0;
        __syncthreads();
        sd[tid] += t;
        __syncthreads();
    }
    int ex = sd[tid] - s;
    int g0 = obase + ex, g1 = obase + ex + c0;

    int node0 = b * BNODES + 2 * tid;
    if (node0 < N) {
        offsets[node0] = g0;
        dinv1[node0] = rsqrtf((float)(c0 + 1));
        dinv2[node0] = c0 ? rsqrtf((float)c0) : 0.0f;
    }
    if (node0 + 1 < N) {
        offsets[node0 + 1] = g1;
        dinv1[node0 + 1] = rsqrtf((float)(c1 + 1));
        dinv2[node0 + 1] = c1 ? rsqrtf((float)c1) : 0.0f;
    }
    __syncthreads();
    cnt[2 * tid] = g0;
    cnt[2 * tid + 1] = g1;
    __syncthreads();

    for (int i = tbeg + tid; i < tend; i += 512) {
        unsigned int v = tmp[i];
        int p = atomicAdd(&cnt[v >> 17], 1);
        sorted_src[p] = (int)(v & 0x1FFFFu);
    }
}

// ---------------- MFMA GEMM: Xs = bf16((in_feat @ W1) * dinv1), 4 tiles/wave ----------------
__global__ __launch_bounds__(256) void gemm_kernel(const float* __restrict__ A,
                                                   const uint4* __restrict__ wfrag,
                                                   const float* __restrict__ dinv1,
                                                   unsigned short* __restrict__ Xs, int nTiles) {
    int wid = blockIdx.x * 4 + (threadIdx.x >> 6);
    int lane = threadIdx.x & 63;
    int lrow = lane & 15, lk = lane >> 4;

    short8 wf[16];
    #pragma unroll
    for (int i = 0; i < 16; ++i)
        wf[i] = *reinterpret_cast<const short8*>(&wfrag[i * 64 + lane]);

    #pragma unroll
    for (int tt = 0; tt < 4; ++tt) {
        int t = wid * 4 + tt;
        if (t >= nTiles) break;
        int node = t * 16 + lrow;
        const float4* ap = reinterpret_cast<const float4*>(A + (size_t)node * IN_F);

        short8 af[4];
        #pragma unroll
        for (int kc = 0; kc < 4; ++kc) {
            float4 x = ap[kc * 8 + lk * 2];
            float4 y = ap[kc * 8 + lk * 2 + 1];
            U16x8 u;
            u.us[0] = f2bf(x.x); u.us[1] = f2bf(x.y); u.us[2] = f2bf(x.z); u.us[3] = f2bf(x.w);
            u.us[4] = f2bf(y.x); u.us[5] = f2bf(y.y); u.us[6] = f2bf(y.z); u.us[7] = f2bf(y.w);
            af[kc] = u.v;
        }

        float dv = dinv1[node];
        #pragma unroll
        for (int ct = 0; ct < 4; ++ct) {
            floatx4 acc = {0.f, 0.f, 0.f, 0.f};
            acc = __builtin_amdgcn_mfma_f32_16x16x32_bf16(wf[ct * 4 + 0], af[0], acc, 0, 0, 0);
            acc = __builtin_amdgcn_mfma_f32_16x16x32_bf16(wf[ct * 4 + 1], af[1], acc, 0, 0, 0);
            acc = __builtin_amdgcn_mfma_f32_16x16x32_bf16(wf[ct * 4 + 2], af[2], acc, 0, 0, 0);
            acc = __builtin_amdgcn_mfma_f32_16x16x32_bf16(wf[ct * 4 + 3], af[3], acc, 0, 0, 0);
            uint2 o;
            o.x = pk2(acc[0] * dv, acc[1] * dv);
            o.y = pk2(acc[2] * dv, acc[3] * dv);
            *reinterpret_cast<uint2*>(Xs + (size_t)node * H_F + ct * 16 + lk * 4) = o;
        }
    }
}

// ---------------- prop1: 4 nodes/wave, 16-lane group per node, MLP 8 ----------------
// h1[d] = dinv1[d]*(sum Xs[s] + Xs[d]);  h1s[d] = h1[d]*dinv2[d]
__global__ __launch_bounds__(256) void prop1_kernel(const int* __restrict__ offsets,
                                                    const int* __restrict__ sorted_src,
                                                    const unsigned short* __restrict__ Xs,
                                                    const float* __restrict__ dinv1,
                                                    const float* __restrict__ dinv2,
                                                    unsigned short* __restrict__ h1,
                                                    unsigned short* __restrict__ h1s, int N) {
    int wid  = (blockIdx.x * blockDim.x + threadIdx.x) >> 6;
    int lane = threadIdx.x & 63;
    int g = lane >> 4, fl = lane & 15;
    int d = wid * 4 + g;
    bool active = d < N;
    int dd = active ? d : N - 1;

    int beg = offsets[dd], end = offsets[dd + 1];
    int gb = g << 4;
    float c0 = 0.f, c1 = 0.f, c2 = 0.f, c3 = 0.f;

    for (int i0 = beg; i0 < end; i0 += 16) {
        int lim = end - i0;
        int s_l = (fl < lim) ? sorted_src[i0 + fl] : ZROW;
        uint2 v[8];
        #pragma unroll
        for (int j = 0; j < 8; ++j) {
            int s = __shfl(s_l, gb + j);
            v[j] = *reinterpret_cast<const uint2*>(Xs + ((size_t)s << 6) + (fl << 2));
        }
        #pragma unroll
        for (int j = 0; j < 8; ++j) {
            c0 += bflo(v[j].x); c1 += bfhi(v[j].x); c2 += bflo(v[j].y); c3 += bfhi(v[j].y);
        }
        #pragma unroll
        for (int j = 0; j < 8; ++j) {
            int s = __shfl(s_l, gb + 8 + j);
            v[j] = *reinterpret_cast<const uint2*>(Xs + ((size_t)s << 6) + (fl << 2));
        }
        #pragma unroll
        for (int j = 0; j < 8; ++j) {
            c0 += bflo(v[j].x); c1 += bfhi(v[j].x); c2 += bflo(v[j].y); c3 += bfhi(v[j].y);
        }
    }

    float dv  = dinv1[dd];
    float dv2 = dinv2[dd];
    uint2 sv = *reinterpret_cast<const uint2*>(Xs + ((size_t)dd << 6) + (fl << 2));
    float h0  = dv * (c0 + bflo(sv.x));
    float h1v = dv * (c1 + bfhi(sv.x));
    float h2  = dv * (c2 + bflo(sv.y));
    float h3  = dv * (c3 + bfhi(sv.y));
    if (active) {
        uint2 o1; o1.x = pk2(h0, h1v); o1.y = pk2(h2, h3);
        *reinterpret_cast<uint2*>(h1 + ((size_t)d << 6) + (fl << 2)) = o1;
        uint2 o2; o2.x = pk2(h0 * dv2, h1v * dv2); o2.y = pk2(h2 * dv2, h3 * dv2);
        *reinterpret_cast<uint2*>(h1s + ((size_t)d << 6) + (fl << 2)) = o2;
    }
}

// ---------------- prop2: 4 nodes/wave + alpha combine ----------------
// out[d] = a0*h1[d] + a1*dinv2[d]*sum(h1s[s])
__global__ __launch_bounds__(256) void prop2_kernel(const int* __restrict__ offsets,
                                                    const int* __restrict__ sorted_src,
                                                    const unsigned short* __restrict__ h1,
                                                    const unsigned short* __restrict__ h1s,
                                                    const float* __restrict__ dinv2,
                                                    const float* __restrict__ alphas,
                                                    float* __restrict__ out, int N) {
    int wid  = (blockIdx.x * blockDim.x + threadIdx.x) >> 6;
    int lane = threadIdx.x & 63;
    int g = lane >> 4, fl = lane & 15;
    int d = wid * 4 + g;
    bool active = d < N;
    int dd = active ? d : N - 1;

    float e0 = expf(alphas[0]), e1 = expf(alphas[1]);
    float aw0 = e0 / (e0 + e1), aw1 = e1 / (e0 + e1);

    int beg = offsets[dd], end = offsets[dd + 1];
    int gb = g << 4;
    float c0 = 0.f, c1 = 0.f, c2 = 0.f, c3 = 0.f;

    for (int i0 = beg; i0 < end; i0 += 16) {
        int lim = end - i0;
        int s_l = (fl < lim) ? sorted_src[i0 + fl] : ZROW;
        uint2 v[8];
        #pragma unroll
        for (int j = 0; j < 8; ++j) {
            int s = __shfl(s_l, gb + j);
            v[j] = *reinterpret_cast<const uint2*>(h1s + ((size_t)s << 6) + (fl << 2));
        }
        #pragma unroll
        for (int j = 0; j < 8; ++j) {
            c0 += bflo(v[j].x); c1 += bfhi(v[j].x); c2 += bflo(v[j].y); c3 += bfhi(v[j].y);
        }
        #pragma unroll
        for (int j = 0; j < 8; ++j) {
            int s = __shfl(s_l, gb + 8 + j);
            v[j] = *reinterpret_cast<const uint2*>(h1s + ((size_t)s << 6) + (fl << 2));
        }
        #pragma unroll
        for (int j = 0; j < 8; ++j) {
            c0 += bflo(v[j].x); c1 += bfhi(v[j].x); c2 += bflo(v[j].y); c3 += bfhi(v[j].y);
        }
    }

    if (active) {
        float sa1 = aw1 * dinv2[dd];
        uint2 sv = *reinterpret_cast<const uint2*>(h1 + ((size_t)d << 6) + (fl << 2));
        float4 o;
        o.x = aw0 * bflo(sv.x) + sa1 * c0;
        o.y = aw0 * bfhi(sv.x) + sa1 * c1;
        o.z = aw0 * bflo(sv.y) + sa1 * c2;
        o.w = aw0 * bfhi(sv.y) + sa1 * c3;
        *reinterpret_cast<float4*>(out + ((size_t)d << 6) + (fl << 2)) = o;
    }
}

extern "C" void kernel_launch(void* const* d_in, const int* in_sizes, int n_in,
                              void* d_out, int out_size, void* d_ws, size_t ws_size,
                              hipStream_t stream) {
    const int*   edge_index = (const int*)d_in[0];   // [2, E]
    const float* in_feat    = (const float*)d_in[1]; // [N, 128]
    const float* W1         = (const float*)d_in[2]; // [128, 64]
    const float* alphas     = (const float*)d_in[3]; // [2]
    float*       out        = (float*)d_out;         // [N, 64]

    const int* src = edge_index;
    const int* dst = edge_index + N_EDGES;

    // workspace layout (bf16 tables: (N+16) rows of 64 bf16; row N = zero sentinel)
    char* ws = (char*)d_ws;
    size_t tabBytes = (size_t)(N_NODES + 16) * H_F * 2;
    unsigned short* Xs  = (unsigned short*)(ws);                 // 12.8 MB
    unsigned int*   tmp = (unsigned int*)(ws);                   // 7.84 MB — aliases Xs (dead until gemm)
    unsigned short* h1  = (unsigned short*)(ws + tabBytes);      // 12.8 MB
    unsigned short* h1s = (unsigned short*)(ws + 2 * tabBytes);  // 12.8 MB
    char* p = ws + 3 * tabBytes;
    int*   sorted = (int*)p;   p += (size_t)N_EDGES * 4;         // 6.4 MB
    int*   offs   = (int*)p;   p += (size_t)(N_NODES + 4) * 4;
    float* dinv1  = (float*)p; p += (size_t)N_NODES * 4;
    float* dinv2  = (float*)p; p += (size_t)N_NODES * 4;
    int*   cofs   = (int*)p;   p += (size_t)(NBKT + 1) * 4;
    int*   ccur   = (int*)p;   p += (size_t)NBKT * 4;
    unsigned int* wfrag = (unsigned int*)p; p += 8192 * 4;       // 32 KB packed W frags

    // zero sentinel rows (row index N) for the two gather tables
    hipMemsetAsync(Xs  + (size_t)N_NODES * H_F, 0, H_F * 2, stream);
    hipMemsetAsync(h1s + (size_t)N_NODES * H_F, 0, H_F * 2, stream);

    init_kernel<<<1, 128, 0, stream>>>(ccur, offs);
    wpack_kernel<<<32, 256, 0, stream>>>(W1, wfrag);
    coarse_scatter_kernel<<<(N_EDGES + EPB - 1) / EPB, 256, 0, stream>>>(src, dst, ccur, tmp, N_EDGES);
    scan98_kernel<<<1, 64, 0, stream>>>(ccur, cofs);
    bucket_kernel<<<NBKT, 512, 0, stream>>>(tmp, ccur, cofs, offs, sorted, dinv1, dinv2, N_NODES);

    // gemm after bucket_kernel (tmp aliases Xs; needs dinv1)
    int nTiles = N_NODES / 16;                        // 6250
    int gemm_waves = (nTiles + 3) / 4;                // 1563
    gemm_kernel<<<(gemm_waves + 3) / 4, 256, 0, stream>>>(in_feat, (const uint4*)wfrag, dinv1, Xs, nTiles);

    int pwaves  = (N_NODES + 3) / 4;                  // 25000 waves, 4 nodes each
    int pblocks = (pwaves + 3) / 4;                   // 6250 blocks of 256
    prop1_kernel<<<pblocks, 256, 0, stream>>>(offs, sorted, Xs, dinv1, dinv2, h1, h1s, N_NODES);
    prop2_kernel<<<pblocks, 256, 0, stream>>>(offs, sorted, h1, h1s, dinv2, alphas, out, N_NODES);
}

// Round 10
// 135.198 us; speedup vs baseline: 1.5115x; 1.0333x over previous
//
#include <hip/hip_runtime.h>

#define N_NODES 100000
#define N_EDGES 1600000
#define IN_F 128
#define H_F 64
#define ZROW N_NODES    // zero sentinel row index in gather tables

#define BSH 10          // coarse bucket = dst >> 10
#define BNODES 1024     // nodes per bucket
#define NBKT 98         // ceil(100000 / 1024)
#define EPB 4096        // edges per block in coarse scatter
#define BCAP 20000      // slack capacity per coarse bucket in tmp (mean 16327, +29 sigma)

typedef short short8 __attribute__((ext_vector_type(8)));
typedef float floatx4 __attribute__((ext_vector_type(4)));

union U16x8 { short8 v; unsigned short us[8]; unsigned int u[4]; };

// ---- bf16 helpers ----
static __device__ __forceinline__ unsigned short f2bf(float f) {
    unsigned int u = __float_as_uint(f);
    unsigned int r = (u + 0x7FFFu + ((u >> 16) & 1u)) >> 16;
    return (unsigned short)r;
}
static __device__ __forceinline__ float bf2f(unsigned short v) {
    return __uint_as_float(((unsigned int)v) << 16);
}
static __device__ __forceinline__ float bflo(unsigned int u) {
    return __uint_as_float(u << 16);
}
static __device__ __forceinline__ float bfhi(unsigned int u) {
    return __uint_as_float(u & 0xFFFF0000u);
}
static __device__ __forceinline__ unsigned int pk2(float a, float b) {
    return (unsigned int)f2bf(a) | ((unsigned int)f2bf(b) << 16);
}

// ---------------- init: slack cursors + prop sentinel + zero sentinel rows ----------------
// replaces hipMemsetAsync (runtime fill kernel cost ~39us per call in-graph!)
__global__ void init_kernel(int* __restrict__ ccur, int* __restrict__ offsets,
                            unsigned int* __restrict__ XsZ, unsigned int* __restrict__ h1sZ) {
    int i = threadIdx.x;
    if (i < NBKT) ccur[i] = i * BCAP;
    if (i == 0) offsets[N_NODES] = N_EDGES;
    if (i < 32) XsZ[i] = 0;                 // Xs sentinel row (64 bf16 = 32 uints)
    else if (i < 64) h1sZ[i - 32] = 0;      // h1s sentinel row
}

// ---------------- W fragment pre-pack ----------------
__global__ __launch_bounds__(256) void wpack_kernel(const float* __restrict__ W,
                                                    unsigned int* __restrict__ wfrag) {
    int i = blockIdx.x * 256 + threadIdx.x;   // [0, 8192)
    int reg = i & 3, lane = (i >> 2) & 63, fkc = i >> 8;
    int ct = fkc >> 2, kc = fkc & 3;
    int fcol = ct * 16 + (lane & 15);
    int k = kc * 32 + (lane >> 4) * 8 + reg * 2;
    wfrag[i] = pk2(W[k * 64 + fcol], W[(k + 1) * 64 + fcol]);
}

// ---------------- pass 1: coarse scatter into slack buckets ----------------
__global__ __launch_bounds__(256) void coarse_scatter_kernel(const int* __restrict__ src,
                                                             const int* __restrict__ dst,
                                                             int* __restrict__ ccur,
                                                             unsigned int* __restrict__ tmp, int E) {
    __shared__ unsigned int buf[EPB];               // 16 KB
    __shared__ unsigned char bktA[EPB];             // 4 KB
    __shared__ int cnt[NBKT], lofs[NBKT], gofs[NBKT];
    int base = blockIdx.x * EPB;
    int n = E - base; if (n > EPB) n = EPB;

    for (int i = threadIdx.x; i < NBKT; i += 256) cnt[i] = 0;
    __syncthreads();

    unsigned int v[16]; int bk[16], loc[16];
    #pragma unroll
    for (int j = 0; j < 16; ++j) {
        int o = threadIdx.x + j * 256;
        bk[j] = -1;
        if (o < n) {
            int s = src[base + o];
            int d = dst[base + o];
            bk[j]  = d >> BSH;
            v[j]   = ((unsigned int)(d & (BNODES - 1)) << 17) | (unsigned int)s;
            loc[j] = atomicAdd(&cnt[bk[j]], 1);
        }
    }
    __syncthreads();
    if (threadIdx.x == 0) {
        int run = 0;
        for (int b = 0; b < NBKT; ++b) { lofs[b] = run; run += cnt[b]; }
    }
    __syncthreads();
    if (threadIdx.x < NBKT && cnt[threadIdx.x] > 0)
        gofs[threadIdx.x] = atomicAdd(&ccur[threadIdx.x], cnt[threadIdx.x]);
    __syncthreads();
    #pragma unroll
    for (int j = 0; j < 16; ++j)
        if (bk[j] >= 0) {
            int p = lofs[bk[j]] + loc[j];
            buf[p]  = v[j];
            bktA[p] = (unsigned char)bk[j];
        }
    __syncthreads();
    for (int i = threadIdx.x; i < n; i += 256) {
        int b = bktA[i];
        tmp[gofs[b] + (i - lofs[b])] = buf[i];
    }
}

// ---------------- scan over 98 bucket counts -> contiguous output bases ----------------
__global__ void scan98_kernel(const int* __restrict__ ccur, int* __restrict__ cofs) {
    if (threadIdx.x == 0) {
        int run = 0;
        for (int b = 0; b < NBKT; ++b) {
            cofs[b] = run;
            run += ccur[b] - b * BCAP;   // count in bucket b
        }
        cofs[NBKT] = run;                // == E
    }
}

// ---------------- pass 2: per-bucket LDS pipeline ----------------
__global__ __launch_bounds__(512) void bucket_kernel(const unsigned int* __restrict__ tmp,
                                                     const int* __restrict__ ccur,
                                                     const int* __restrict__ cofs,
                                                     int* __restrict__ offsets,
                                                     int* __restrict__ sorted_src,
                                                     float* __restrict__ dinv1,
                                                     float* __restrict__ dinv2, int N) {
    __shared__ int cnt[BNODES];
    __shared__ int sd[512];
    int b   = blockIdx.x;
    int tid = threadIdx.x;
    int tbeg = b * BCAP, tend = ccur[b];   // bucket's run in tmp (slack layout)
    int obase = cofs[b];                   // contiguous base in sorted_src

    for (int i = tid; i < BNODES; i += 512) cnt[i] = 0;
    __syncthreads();
    for (int i = tbeg + tid; i < tend; i += 512)
        atomicAdd(&cnt[tmp[i] >> 17], 1);
    __syncthreads();

    int c0 = cnt[2 * tid], c1 = cnt[2 * tid + 1];
    int s  = c0 + c1;
    sd[tid] = s;
    __syncthreads();
    for (int off = 1; off < 512; off <<= 1) {
        int t = (tid >= off) ? sd[tid - off] : 0;
        __syncthreads();
        sd[tid] += t;
        __syncthreads();
    }
    int ex = sd[tid] - s;
    int g0 = obase + ex, g1 = obase + ex + c0;

    int node0 = b * BNODES + 2 * tid;
    if (node0 < N) {
        offsets[node0] = g0;
        dinv1[node0] = rsqrtf((float)(c0 + 1));
        dinv2[node0] = c0 ? rsqrtf((float)c0) : 0.0f;
    }
    if (node0 + 1 < N) {
        offsets[node0 + 1] = g1;
        dinv1[node0 + 1] = rsqrtf((float)(c1 + 1));
        dinv2[node0 + 1] = c1 ? rsqrtf((float)c1) : 0.0f;
    }
    __syncthreads();
    cnt[2 * tid] = g0;
    cnt[2 * tid + 1] = g1;
    __syncthreads();

    for (int i = tbeg + tid; i < tend; i += 512) {
        unsigned int v = tmp[i];
        int p = atomicAdd(&cnt[v >> 17], 1);
        sorted_src[p] = (int)(v & 0x1FFFFu);
    }
}

// ---------------- MFMA GEMM: Xs = bf16((in_feat @ W1) * dinv1), 4 tiles/wave ----------------
__global__ __launch_bounds__(256) void gemm_kernel(const float* __restrict__ A,
                                                   const uint4* __restrict__ wfrag,
                                                   const float* __restrict__ dinv1,
                                                   unsigned short* __restrict__ Xs, int nTiles) {
    int wid = blockIdx.x * 4 + (threadIdx.x >> 6);
    int lane = threadIdx.x & 63;
    int lrow = lane & 15, lk = lane >> 4;

    short8 wf[16];
    #pragma unroll
    for (int i = 0; i < 16; ++i)
        wf[i] = *reinterpret_cast<const short8*>(&wfrag[i * 64 + lane]);

    #pragma unroll
    for (int tt = 0; tt < 4; ++tt) {
        int t = wid * 4 + tt;
        if (t >= nTiles) break;
        int node = t * 16 + lrow;
        const float4* ap = reinterpret_cast<const float4*>(A + (size_t)node * IN_F);

        short8 af[4];
        #pragma unroll
        for (int kc = 0; kc < 4; ++kc) {
            float4 x = ap[kc * 8 + lk * 2];
            float4 y = ap[kc * 8 + lk * 2 + 1];
            U16x8 u;
            u.us[0] = f2bf(x.x); u.us[1] = f2bf(x.y); u.us[2] = f2bf(x.z); u.us[3] = f2bf(x.w);
            u.us[4] = f2bf(y.x); u.us[5] = f2bf(y.y); u.us[6] = f2bf(y.z); u.us[7] = f2bf(y.w);
            af[kc] = u.v;
        }

        float dv = dinv1[node];
        #pragma unroll
        for (int ct = 0; ct < 4; ++ct) {
            floatx4 acc = {0.f, 0.f, 0.f, 0.f};
            acc = __builtin_amdgcn_mfma_f32_16x16x32_bf16(wf[ct * 4 + 0], af[0], acc, 0, 0, 0);
            acc = __builtin_amdgcn_mfma_f32_16x16x32_bf16(wf[ct * 4 + 1], af[1], acc, 0, 0, 0);
            acc = __builtin_amdgcn_mfma_f32_16x16x32_bf16(wf[ct * 4 + 2], af[2], acc, 0, 0, 0);
            acc = __builtin_amdgcn_mfma_f32_16x16x32_bf16(wf[ct * 4 + 3], af[3], acc, 0, 0, 0);
            uint2 o;
            o.x = pk2(acc[0] * dv, acc[1] * dv);
            o.y = pk2(acc[2] * dv, acc[3] * dv);
            *reinterpret_cast<uint2*>(Xs + (size_t)node * H_F + ct * 16 + lk * 4) = o;
        }
    }
}

// ---------------- prop1: 4 nodes/wave, 16-lane group per node, MLP 8 ----------------
// h1[d] = dinv1[d]*(sum Xs[s] + Xs[d]);  h1s[d] = h1[d]*dinv2[d]
__global__ __launch_bounds__(256) void prop1_kernel(const int* __restrict__ offsets,
                                                    const int* __restrict__ sorted_src,
                                                    const unsigned short* __restrict__ Xs,
                                                    const float* __restrict__ dinv1,
                                                    const float* __restrict__ dinv2,
                                                    unsigned short* __restrict__ h1,
                                                    unsigned short* __restrict__ h1s, int N) {
    int wid  = (blockIdx.x * blockDim.x + threadIdx.x) >> 6;
    int lane = threadIdx.x & 63;
    int g = lane >> 4, fl = lane & 15;
    int d = wid * 4 + g;
    bool active = d < N;
    int dd = active ? d : N - 1;

    int beg = offsets[dd], end = offsets[dd + 1];
    int gb = g << 4;
    float c0 = 0.f, c1 = 0.f, c2 = 0.f, c3 = 0.f;

    for (int i0 = beg; i0 < end; i0 += 16) {
        int lim = end - i0;
        int s_l = (fl < lim) ? sorted_src[i0 + fl] : ZROW;
        uint2 v[8];
        #pragma unroll
        for (int j = 0; j < 8; ++j) {
            int s = __shfl(s_l, gb + j);
            v[j] = *reinterpret_cast<const uint2*>(Xs + ((size_t)s << 6) + (fl << 2));
        }
        #pragma unroll
        for (int j = 0; j < 8; ++j) {
            c0 += bflo(v[j].x); c1 += bfhi(v[j].x); c2 += bflo(v[j].y); c3 += bfhi(v[j].y);
        }
        #pragma unroll
        for (int j = 0; j < 8; ++j) {
            int s = __shfl(s_l, gb + 8 + j);
            v[j] = *reinterpret_cast<const uint2*>(Xs + ((size_t)s << 6) + (fl << 2));
        }
        #pragma unroll
        for (int j = 0; j < 8; ++j) {
            c0 += bflo(v[j].x); c1 += bfhi(v[j].x); c2 += bflo(v[j].y); c3 += bfhi(v[j].y);
        }
    }

    float dv  = dinv1[dd];
    float dv2 = dinv2[dd];
    uint2 sv = *reinterpret_cast<const uint2*>(Xs + ((size_t)dd << 6) + (fl << 2));
    float h0  = dv * (c0 + bflo(sv.x));
    float h1v = dv * (c1 + bfhi(sv.x));
    float h2  = dv * (c2 + bflo(sv.y));
    float h3  = dv * (c3 + bfhi(sv.y));
    if (active) {
        uint2 o1; o1.x = pk2(h0, h1v); o1.y = pk2(h2, h3);
        *reinterpret_cast<uint2*>(h1 + ((size_t)d << 6) + (fl << 2)) = o1;
        uint2 o2; o2.x = pk2(h0 * dv2, h1v * dv2); o2.y = pk2(h2 * dv2, h3 * dv2);
        *reinterpret_cast<uint2*>(h1s + ((size_t)d << 6) + (fl << 2)) = o2;
    }
}

// ---------------- prop2: 4 nodes/wave + alpha combine ----------------
// out[d] = a0*h1[d] + a1*dinv2[d]*sum(h1s[s])
__global__ __launch_bounds__(256) void prop2_kernel(const int* __restrict__ offsets,
                                                    const int* __restrict__ sorted_src,
                                                    const unsigned short* __restrict__ h1,
                                                    const unsigned short* __restrict__ h1s,
                                                    const float* __restrict__ dinv2,
                                                    const float* __restrict__ alphas,
                                                    float* __restrict__ out, int N) {
    int wid  = (blockIdx.x * blockDim.x + threadIdx.x) >> 6;
    int lane = threadIdx.x & 63;
    int g = lane >> 4, fl = lane & 15;
    int d = wid * 4 + g;
    bool active = d < N;
    int dd = active ? d : N - 1;

    float e0 = expf(alphas[0]), e1 = expf(alphas[1]);
    float aw0 = e0 / (e0 + e1), aw1 = e1 / (e0 + e1);

    int beg = offsets[dd], end = offsets[dd + 1];
    int gb = g << 4;
    float c0 = 0.f, c1 = 0.f, c2 = 0.f, c3 = 0.f;

    for (int i0 = beg; i0 < end; i0 += 16) {
        int lim = end - i0;
        int s_l = (fl < lim) ? sorted_src[i0 + fl] : ZROW;
        uint2 v[8];
        #pragma unroll
        for (int j = 0; j < 8; ++j) {
            int s = __shfl(s_l, gb + j);
            v[j] = *reinterpret_cast<const uint2*>(h1s + ((size_t)s << 6) + (fl << 2));
        }
        #pragma unroll
        for (int j = 0; j < 8; ++j) {
            c0 += bflo(v[j].x); c1 += bfhi(v[j].x); c2 += bflo(v[j].y); c3 += bfhi(v[j].y);
        }
        #pragma unroll
        for (int j = 0; j < 8; ++j) {
            int s = __shfl(s_l, gb + 8 + j);
            v[j] = *reinterpret_cast<const uint2*>(h1s + ((size_t)s << 6) + (fl << 2));
        }
        #pragma unroll
        for (int j = 0; j < 8; ++j) {
            c0 += bflo(v[j].x); c1 += bfhi(v[j].x); c2 += bflo(v[j].y); c3 += bfhi(v[j].y);
        }
    }

    if (active) {
        float sa1 = aw1 * dinv2[dd];
        uint2 sv = *reinterpret_cast<const uint2*>(h1 + ((size_t)d << 6) + (fl << 2));
        float4 o;
        o.x = aw0 * bflo(sv.x) + sa1 * c0;
        o.y = aw0 * bfhi(sv.x) + sa1 * c1;
        o.z = aw0 * bflo(sv.y) + sa1 * c2;
        o.w = aw0 * bfhi(sv.y) + sa1 * c3;
        *reinterpret_cast<float4*>(out + ((size_t)d << 6) + (fl << 2)) = o;
    }
}

extern "C" void kernel_launch(void* const* d_in, const int* in_sizes, int n_in,
                              void* d_out, int out_size, void* d_ws, size_t ws_size,
                              hipStream_t stream) {
    const int*   edge_index = (const int*)d_in[0];   // [2, E]
    const float* in_feat    = (const float*)d_in[1]; // [N, 128]
    const float* W1         = (const float*)d_in[2]; // [128, 64]
    const float* alphas     = (const float*)d_in[3]; // [2]
    float*       out        = (float*)d_out;         // [N, 64]

    const int* src = edge_index;
    const int* dst = edge_index + N_EDGES;

    // workspace layout (bf16 tables: (N+16) rows of 64 bf16; row N = zero sentinel)
    char* ws = (char*)d_ws;
    size_t tabBytes = (size_t)(N_NODES + 16) * H_F * 2;
    unsigned short* Xs  = (unsigned short*)(ws);                 // 12.8 MB
    unsigned int*   tmp = (unsigned int*)(ws);                   // 7.84 MB — aliases Xs rows [0, ~61k); sentinel (12.8 MB) untouched
    unsigned short* h1  = (unsigned short*)(ws + tabBytes);      // 12.8 MB
    unsigned short* h1s = (unsigned short*)(ws + 2 * tabBytes);  // 12.8 MB
    char* p = ws + 3 * tabBytes;
    int*   sorted = (int*)p;   p += (size_t)N_EDGES * 4;         // 6.4 MB
    int*   offs   = (int*)p;   p += (size_t)(N_NODES + 4) * 4;
    float* dinv1  = (float*)p; p += (size_t)N_NODES * 4;
    float* dinv2  = (float*)p; p += (size_t)N_NODES * 4;
    int*   cofs   = (int*)p;   p += (size_t)(NBKT + 1) * 4;
    int*   ccur   = (int*)p;   p += (size_t)NBKT * 4;
    unsigned int* wfrag = (unsigned int*)p; p += 8192 * 4;       // 32 KB packed W frags

    init_kernel<<<1, 128, 0, stream>>>(ccur, offs,
                                       (unsigned int*)(Xs + (size_t)N_NODES * H_F),
                                       (unsigned int*)(h1s + (size_t)N_NODES * H_F));
    wpack_kernel<<<32, 256, 0, stream>>>(W1, wfrag);
    coarse_scatter_kernel<<<(N_EDGES + EPB - 1) / EPB, 256, 0, stream>>>(src, dst, ccur, tmp, N_EDGES);
    scan98_kernel<<<1, 64, 0, stream>>>(ccur, cofs);
    bucket_kernel<<<NBKT, 512, 0, stream>>>(tmp, ccur, cofs, offs, sorted, dinv1, dinv2, N_NODES);

    // gemm after bucket_kernel (tmp aliases Xs; needs dinv1)
    int nTiles = N_NODES / 16;                        // 6250
    int gemm_waves = (nTiles + 3) / 4;                // 1563
    gemm_kernel<<<(gemm_waves + 3) / 4, 256, 0, stream>>>(in_feat, (const uint4*)wfrag, dinv1, Xs, nTiles);

    int pwaves  = (N_NODES + 3) / 4;                  // 25000 waves, 4 nodes each
    int pblocks = (pwaves + 3) / 4;                   // 6250 blocks of 256
    prop1_kernel<<<pblocks, 256, 0, stream>>>(offs, sorted, Xs, dinv1, dinv2, h1, h1s, N_NODES);
    prop2_kernel<<<pblocks, 256, 0, stream>>>(offs, sorted, h1, h1s, dinv2, alphas, out, N_NODES);
}

// Round 11
// 131.351 us; speedup vs baseline: 1.5558x; 1.0293x over previous
//
#include <hip/hip_runtime.h>

#define N_NODES 100000
#define N_EDGES 1600000
#define IN_F 128
#define H_F 64
#define ZROW N_NODES    // zero sentinel row index in gather tables

#define BSH 10          // coarse bucket = dst >> 10
#define BNODES 1024     // nodes per bucket
#define NBKT 98         // ceil(100000 / 1024)
#define EPB 4096        // edges per block in coarse scatter
#define BCAP 20000      // slack capacity per coarse bucket in tmp (mean 16327, +29 sigma)

typedef short short8 __attribute__((ext_vector_type(8)));
typedef float floatx4 __attribute__((ext_vector_type(4)));

union U16x8 { short8 v; unsigned short us[8]; unsigned int u[4]; };

// ---- bf16 helpers ----
static __device__ __forceinline__ unsigned short f2bf(float f) {
    unsigned int u = __float_as_uint(f);
    unsigned int r = (u + 0x7FFFu + ((u >> 16) & 1u)) >> 16;
    return (unsigned short)r;
}
static __device__ __forceinline__ float bf2f(unsigned short v) {
    return __uint_as_float(((unsigned int)v) << 16);
}
static __device__ __forceinline__ float bflo(unsigned int u) {
    return __uint_as_float(u << 16);
}
static __device__ __forceinline__ float bfhi(unsigned int u) {
    return __uint_as_float(u & 0xFFFF0000u);
}
static __device__ __forceinline__ unsigned int pk2(float a, float b) {
    return (unsigned int)f2bf(a) | ((unsigned int)f2bf(b) << 16);
}

// ---------------- fused init + W fragment pre-pack ----------------
// 32 blocks: all do wpack; block 0 additionally sets cursors/sentinels.
__global__ __launch_bounds__(256) void initwpack_kernel(const float* __restrict__ W,
                                                        unsigned int* __restrict__ wfrag,
                                                        int* __restrict__ ccur,
                                                        int* __restrict__ offsets,
                                                        unsigned int* __restrict__ XsZ,
                                                        unsigned int* __restrict__ h1sZ) {
    int i = blockIdx.x * 256 + threadIdx.x;   // [0, 8192)
    int reg = i & 3, lane = (i >> 2) & 63, fkc = i >> 8;
    int ct = fkc >> 2, kc = fkc & 3;
    int fcol = ct * 16 + (lane & 15);
    int k = kc * 32 + (lane >> 4) * 8 + reg * 2;
    wfrag[i] = pk2(W[k * 64 + fcol], W[(k + 1) * 64 + fcol]);

    if (blockIdx.x == 0) {
        int t = threadIdx.x;
        if (t < NBKT) ccur[t] = t * BCAP;
        if (t == 0) offsets[N_NODES] = N_EDGES;
        if (t < 32) XsZ[t] = 0;                 // Xs sentinel row (64 bf16 = 32 uints)
        else if (t < 64) h1sZ[t - 32] = 0;      // h1s sentinel row
    }
}

// ---------------- pass 1: coarse scatter into slack buckets ----------------
__global__ __launch_bounds__(256) void coarse_scatter_kernel(const int* __restrict__ src,
                                                             const int* __restrict__ dst,
                                                             int* __restrict__ ccur,
                                                             unsigned int* __restrict__ tmp, int E) {
    __shared__ unsigned int buf[EPB];               // 16 KB
    __shared__ unsigned char bktA[EPB];             // 4 KB
    __shared__ int cnt[NBKT], lofs[NBKT], gofs[NBKT];
    int base = blockIdx.x * EPB;
    int n = E - base; if (n > EPB) n = EPB;

    for (int i = threadIdx.x; i < NBKT; i += 256) cnt[i] = 0;
    __syncthreads();

    unsigned int v[16]; int bk[16], loc[16];
    #pragma unroll
    for (int j = 0; j < 16; ++j) {
        int o = threadIdx.x + j * 256;
        bk[j] = -1;
        if (o < n) {
            int s = src[base + o];
            int d = dst[base + o];
            bk[j]  = d >> BSH;
            v[j]   = ((unsigned int)(d & (BNODES - 1)) << 17) | (unsigned int)s;
            loc[j] = atomicAdd(&cnt[bk[j]], 1);
        }
    }
    __syncthreads();
    if (threadIdx.x == 0) {
        int run = 0;
        for (int b = 0; b < NBKT; ++b) { lofs[b] = run; run += cnt[b]; }
    }
    __syncthreads();
    if (threadIdx.x < NBKT && cnt[threadIdx.x] > 0)
        gofs[threadIdx.x] = atomicAdd(&ccur[threadIdx.x], cnt[threadIdx.x]);
    __syncthreads();
    #pragma unroll
    for (int j = 0; j < 16; ++j)
        if (bk[j] >= 0) {
            int p = lofs[bk[j]] + loc[j];
            buf[p]  = v[j];
            bktA[p] = (unsigned char)bk[j];
        }
    __syncthreads();
    for (int i = threadIdx.x; i < n; i += 256) {
        int b = bktA[i];
        tmp[gofs[b] + (i - lofs[b])] = buf[i];
    }
}

// ---------------- pass 2: per-bucket LDS pipeline (self-computed prefix) ----------------
__global__ __launch_bounds__(512) void bucket_kernel(const unsigned int* __restrict__ tmp,
                                                     const int* __restrict__ ccur,
                                                     int* __restrict__ offsets,
                                                     int* __restrict__ sorted_src,
                                                     float* __restrict__ dinv1,
                                                     float* __restrict__ dinv2, int N) {
    __shared__ int cnt[BNODES];
    __shared__ int sd[512];
    __shared__ int obase_s;
    int b   = blockIdx.x;
    int tid = threadIdx.x;
    int tbeg = b * BCAP, tend = ccur[b];   // bucket's run in tmp (slack layout)

    if (tid == 0) {                        // prefix over earlier buckets (98 iters, scalar)
        int run = 0;
        for (int q = 0; q < b; ++q) run += ccur[q] - q * BCAP;
        obase_s = run;
    }
    for (int i = tid; i < BNODES; i += 512) cnt[i] = 0;
    __syncthreads();
    for (int i = tbeg + tid; i < tend; i += 512)
        atomicAdd(&cnt[tmp[i] >> 17], 1);
    __syncthreads();

    int c0 = cnt[2 * tid], c1 = cnt[2 * tid + 1];
    int s  = c0 + c1;
    sd[tid] = s;
    __syncthreads();
    for (int off = 1; off < 512; off <<= 1) {
        int t = (tid >= off) ? sd[tid - off] : 0;
        __syncthreads();
        sd[tid] += t;
        __syncthreads();
    }
    int obase = obase_s;
    int ex = sd[tid] - s;
    int g0 = obase + ex, g1 = obase + ex + c0;

    int node0 = b * BNODES + 2 * tid;
    if (node0 < N) {
        offsets[node0] = g0;
        dinv1[node0] = rsqrtf((float)(c0 + 1));
        dinv2[node0] = c0 ? rsqrtf((float)c0) : 0.0f;
    }
    if (node0 + 1 < N) {
        offsets[node0 + 1] = g1;
        dinv1[node0 + 1] = rsqrtf((float)(c1 + 1));
        dinv2[node0 + 1] = c1 ? rsqrtf((float)c1) : 0.0f;
    }
    __syncthreads();
    cnt[2 * tid] = g0;
    cnt[2 * tid + 1] = g1;
    __syncthreads();

    for (int i = tbeg + tid; i < tend; i += 512) {
        unsigned int v = tmp[i];
        int p = atomicAdd(&cnt[v >> 17], 1);
        sorted_src[p] = (int)(v & 0x1FFFFu);
    }
}

// ---------------- MFMA GEMM: Xs = bf16((in_feat @ W1) * dinv1), 4 tiles/wave ----------------
__global__ __launch_bounds__(256) void gemm_kernel(const float* __restrict__ A,
                                                   const uint4* __restrict__ wfrag,
                                                   const float* __restrict__ dinv1,
                                                   unsigned short* __restrict__ Xs, int nTiles) {
    int wid = blockIdx.x * 4 + (threadIdx.x >> 6);
    int lane = threadIdx.x & 63;
    int lrow = lane & 15, lk = lane >> 4;

    short8 wf[16];
    #pragma unroll
    for (int i = 0; i < 16; ++i)
        wf[i] = *reinterpret_cast<const short8*>(&wfrag[i * 64 + lane]);

    #pragma unroll
    for (int tt = 0; tt < 4; ++tt) {
        int t = wid * 4 + tt;
        if (t >= nTiles) break;
        int node = t * 16 + lrow;
        const float4* ap = reinterpret_cast<const float4*>(A + (size_t)node * IN_F);

        short8 af[4];
        #pragma unroll
        for (int kc = 0; kc < 4; ++kc) {
            float4 x = ap[kc * 8 + lk * 2];
            float4 y = ap[kc * 8 + lk * 2 + 1];
            U16x8 u;
            u.us[0] = f2bf(x.x); u.us[1] = f2bf(x.y); u.us[2] = f2bf(x.z); u.us[3] = f2bf(x.w);
            u.us[4] = f2bf(y.x); u.us[5] = f2bf(y.y); u.us[6] = f2bf(y.z); u.us[7] = f2bf(y.w);
            af[kc] = u.v;
        }

        float dv = dinv1[node];
        #pragma unroll
        for (int ct = 0; ct < 4; ++ct) {
            floatx4 acc = {0.f, 0.f, 0.f, 0.f};
            acc = __builtin_amdgcn_mfma_f32_16x16x32_bf16(wf[ct * 4 + 0], af[0], acc, 0, 0, 0);
            acc = __builtin_amdgcn_mfma_f32_16x16x32_bf16(wf[ct * 4 + 1], af[1], acc, 0, 0, 0);
            acc = __builtin_amdgcn_mfma_f32_16x16x32_bf16(wf[ct * 4 + 2], af[2], acc, 0, 0, 0);
            acc = __builtin_amdgcn_mfma_f32_16x16x32_bf16(wf[ct * 4 + 3], af[3], acc, 0, 0, 0);
            uint2 o;
            o.x = pk2(acc[0] * dv, acc[1] * dv);
            o.y = pk2(acc[2] * dv, acc[3] * dv);
            *reinterpret_cast<uint2*>(Xs + (size_t)node * H_F + ct * 16 + lk * 4) = o;
        }
    }
}

// ---------------- prop1: 4 nodes/wave, 16 gathers in flight per lane ----------------
// h1[d] = dinv1[d]*(sum Xs[s] + Xs[d]);  h1s[d] = h1[d]*dinv2[d]
__global__ __launch_bounds__(256) void prop1_kernel(const int* __restrict__ offsets,
                                                    const int* __restrict__ sorted_src,
                                                    const unsigned short* __restrict__ Xs,
                                                    const float* __restrict__ dinv1,
                                                    const float* __restrict__ dinv2,
                                                    unsigned short* __restrict__ h1,
                                                    unsigned short* __restrict__ h1s, int N) {
    int wid  = (blockIdx.x * blockDim.x + threadIdx.x) >> 6;
    int lane = threadIdx.x & 63;
    int g = lane >> 4, fl = lane & 15;
    int d = wid * 4 + g;
    bool active = d < N;
    int dd = active ? d : N - 1;

    int beg = offsets[dd], end = offsets[dd + 1];
    int gb = g << 4;
    float c0 = 0.f, c1 = 0.f, c2 = 0.f, c3 = 0.f;

    for (int i0 = beg; i0 < end; i0 += 16) {
        int lim = end - i0;
        int s_l = (fl < lim) ? sorted_src[i0 + fl] : ZROW;
        uint2 v[16];
        #pragma unroll
        for (int j = 0; j < 16; ++j) {
            int s = __shfl(s_l, gb + j);
            v[j] = *reinterpret_cast<const uint2*>(Xs + ((size_t)s << 6) + (fl << 2));
        }
        #pragma unroll
        for (int j = 0; j < 16; ++j) {
            c0 += bflo(v[j].x); c1 += bfhi(v[j].x); c2 += bflo(v[j].y); c3 += bfhi(v[j].y);
        }
    }

    float dv  = dinv1[dd];
    float dv2 = dinv2[dd];
    uint2 sv = *reinterpret_cast<const uint2*>(Xs + ((size_t)dd << 6) + (fl << 2));
    float h0  = dv * (c0 + bflo(sv.x));
    float h1v = dv * (c1 + bfhi(sv.x));
    float h2  = dv * (c2 + bflo(sv.y));
    float h3  = dv * (c3 + bfhi(sv.y));
    if (active) {
        uint2 o1; o1.x = pk2(h0, h1v); o1.y = pk2(h2, h3);
        *reinterpret_cast<uint2*>(h1 + ((size_t)d << 6) + (fl << 2)) = o1;
        uint2 o2; o2.x = pk2(h0 * dv2, h1v * dv2); o2.y = pk2(h2 * dv2, h3 * dv2);
        *reinterpret_cast<uint2*>(h1s + ((size_t)d << 6) + (fl << 2)) = o2;
    }
}

// ---------------- prop2: 4 nodes/wave, 16 gathers in flight + alpha combine ----------------
// out[d] = a0*h1[d] + a1*dinv2[d]*sum(h1s[s])
__global__ __launch_bounds__(256) void prop2_kernel(const int* __restrict__ offsets,
                                                    const int* __restrict__ sorted_src,
                                                    const unsigned short* __restrict__ h1,
                                                    const unsigned short* __restrict__ h1s,
                                                    const float* __restrict__ dinv2,
                                                    const float* __restrict__ alphas,
                                                    float* __restrict__ out, int N) {
    int wid  = (blockIdx.x * blockDim.x + threadIdx.x) >> 6;
    int lane = threadIdx.x & 63;
    int g = lane >> 4, fl = lane & 15;
    int d = wid * 4 + g;
    bool active = d < N;
    int dd = active ? d : N - 1;

    float e0 = expf(alphas[0]), e1 = expf(alphas[1]);
    float aw0 = e0 / (e0 + e1), aw1 = e1 / (e0 + e1);

    int beg = offsets[dd], end = offsets[dd + 1];
    int gb = g << 4;
    float c0 = 0.f, c1 = 0.f, c2 = 0.f, c3 = 0.f;

    for (int i0 = beg; i0 < end; i0 += 16) {
        int lim = end - i0;
        int s_l = (fl < lim) ? sorted_src[i0 + fl] : ZROW;
        uint2 v[16];
        #pragma unroll
        for (int j = 0; j < 16; ++j) {
            int s = __shfl(s_l, gb + j);
            v[j] = *reinterpret_cast<const uint2*>(h1s + ((size_t)s << 6) + (fl << 2));
        }
        #pragma unroll
        for (int j = 0; j < 16; ++j) {
            c0 += bflo(v[j].x); c1 += bfhi(v[j].x); c2 += bflo(v[j].y); c3 += bfhi(v[j].y);
        }
    }

    if (active) {
        float sa1 = aw1 * dinv2[dd];
        uint2 sv = *reinterpret_cast<const uint2*>(h1 + ((size_t)d << 6) + (fl << 2));
        float4 o;
        o.x = aw0 * bflo(sv.x) + sa1 * c0;
        o.y = aw0 * bfhi(sv.x) + sa1 * c1;
        o.z = aw0 * bflo(sv.y) + sa1 * c2;
        o.w = aw0 * bfhi(sv.y) + sa1 * c3;
        *reinterpret_cast<float4*>(out + ((size_t)d << 6) + (fl << 2)) = o;
    }
}

extern "C" void kernel_launch(void* const* d_in, const int* in_sizes, int n_in,
                              void* d_out, int out_size, void* d_ws, size_t ws_size,
                              hipStream_t stream) {
    const int*   edge_index = (const int*)d_in[0];   // [2, E]
    const float* in_feat    = (const float*)d_in[1]; // [N, 128]
    const float* W1         = (const float*)d_in[2]; // [128, 64]
    const float* alphas     = (const float*)d_in[3]; // [2]
    float*       out        = (float*)d_out;         // [N, 64]

    const int* src = edge_index;
    const int* dst = edge_index + N_EDGES;

    // workspace layout (bf16 tables: (N+16) rows of 64 bf16; row N = zero sentinel)
    char* ws = (char*)d_ws;
    size_t tabBytes = (size_t)(N_NODES + 16) * H_F * 2;
    unsigned short* Xs  = (unsigned short*)(ws);                 // 12.8 MB
    unsigned int*   tmp = (unsigned int*)(ws);                   // 7.84 MB — aliases Xs rows [0, ~61k); sentinel untouched
    unsigned short* h1  = (unsigned short*)(ws + tabBytes);      // 12.8 MB
    unsigned short* h1s = (unsigned short*)(ws + 2 * tabBytes);  // 12.8 MB
    char* p = ws + 3 * tabBytes;
    int*   sorted = (int*)p;   p += (size_t)N_EDGES * 4;         // 6.4 MB
    int*   offs   = (int*)p;   p += (size_t)(N_NODES + 4) * 4;
    float* dinv1  = (float*)p; p += (size_t)N_NODES * 4;
    float* dinv2  = (float*)p; p += (size_t)N_NODES * 4;
    int*   ccur   = (int*)p;   p += (size_t)NBKT * 4;
    unsigned int* wfrag = (unsigned int*)p; p += 8192 * 4;       // 32 KB packed W frags

    initwpack_kernel<<<32, 256, 0, stream>>>(W1, wfrag, ccur, offs,
                                             (unsigned int*)(Xs + (size_t)N_NODES * H_F),
                                             (unsigned int*)(h1s + (size_t)N_NODES * H_F));
    coarse_scatter_kernel<<<(N_EDGES + EPB - 1) / EPB, 256, 0, stream>>>(src, dst, ccur, tmp, N_EDGES);
    bucket_kernel<<<NBKT, 512, 0, stream>>>(tmp, ccur, offs, sorted, dinv1, dinv2, N_NODES);

    // gemm after bucket_kernel (tmp aliases Xs; needs dinv1)
    int nTiles = N_NODES / 16;                        // 6250
    int gemm_waves = (nTiles + 3) / 4;                // 1563
    gemm_kernel<<<(gemm_waves + 3) / 4, 256, 0, stream>>>(in_feat, (const uint4*)wfrag, dinv1, Xs, nTiles);

    int pwaves  = (N_NODES + 3) / 4;                  // 25000 waves, 4 nodes each
    int pblocks = (pwaves + 3) / 4;                   // 6250 blocks of 256
    prop1_kernel<<<pblocks, 256, 0, stream>>>(offs, sorted, Xs, dinv1, dinv2, h1, h1s, N_NODES);
    prop2_kernel<<<pblocks, 256, 0, stream>>>(offs, sorted, h1, h1s, dinv2, alphas, out, N_NODES);
}

// Round 12
// 129.252 us; speedup vs baseline: 1.5811x; 1.0162x over previous
//
#include <hip/hip_runtime.h>

#define N_NODES 100000
#define N_EDGES 1600000
#define IN_F 128
#define H_F 64
#define ZROW N_NODES    // zero sentinel row index in gather tables

#define BSH 10          // coarse bucket = dst >> 10
#define BNODES 1024     // nodes per bucket
#define NBKT 98         // ceil(100000 / 1024)
#define EPB 4096        // edges per block in coarse scatter
#define BCAP 20000      // slack capacity per coarse bucket in tmp (mean 16327, +29 sigma)
#define SCAP 28192      // slack capacity per bucket in sorted (BCAP + 1024*8 pad)

typedef short short8 __attribute__((ext_vector_type(8)));
typedef float floatx4 __attribute__((ext_vector_type(4)));

union U16x8 { short8 v; unsigned short us[8]; unsigned int u[4]; };

// ---- bf16 helpers ----
static __device__ __forceinline__ unsigned short f2bf(float f) {
    unsigned int u = __float_as_uint(f);
    unsigned int r = (u + 0x7FFFu + ((u >> 16) & 1u)) >> 16;
    return (unsigned short)r;
}
static __device__ __forceinline__ float bflo(unsigned int u) {
    return __uint_as_float(u << 16);
}
static __device__ __forceinline__ float bfhi(unsigned int u) {
    return __uint_as_float(u & 0xFFFF0000u);
}
static __device__ __forceinline__ unsigned int pk2(float a, float b) {
    return (unsigned int)f2bf(a) | ((unsigned int)f2bf(b) << 16);
}

// ---------------- fused init + W fragment pre-pack ----------------
__global__ __launch_bounds__(256) void initwpack_kernel(const float* __restrict__ W,
                                                        unsigned int* __restrict__ wfrag,
                                                        int* __restrict__ ccur,
                                                        unsigned int* __restrict__ XsZ,
                                                        unsigned int* __restrict__ h1sZ) {
    int i = blockIdx.x * 256 + threadIdx.x;   // [0, 8192)
    int reg = i & 3, lane = (i >> 2) & 63, fkc = i >> 8;
    int ct = fkc >> 2, kc = fkc & 3;
    int fcol = ct * 16 + (lane & 15);
    int k = kc * 32 + (lane >> 4) * 8 + reg * 2;
    wfrag[i] = pk2(W[k * 64 + fcol], W[(k + 1) * 64 + fcol]);

    if (blockIdx.x == 0) {
        int t = threadIdx.x;
        if (t < NBKT) ccur[t] = t * BCAP;
        if (t < 32) XsZ[t] = 0;                 // Xs sentinel row (64 bf16 = 32 uints)
        else if (t < 64) h1sZ[t - 32] = 0;      // h1s sentinel row
    }
}

// ---------------- pass 1: coarse scatter into slack buckets ----------------
__global__ __launch_bounds__(256) void coarse_scatter_kernel(const int* __restrict__ src,
                                                             const int* __restrict__ dst,
                                                             int* __restrict__ ccur,
                                                             unsigned int* __restrict__ tmp, int E) {
    __shared__ unsigned int buf[EPB];               // 16 KB
    __shared__ unsigned char bktA[EPB];             // 4 KB
    __shared__ int cnt[NBKT], lofs[NBKT], gofs[NBKT];
    int base = blockIdx.x * EPB;
    int n = E - base; if (n > EPB) n = EPB;

    for (int i = threadIdx.x; i < NBKT; i += 256) cnt[i] = 0;
    __syncthreads();

    unsigned int v[16]; int bk[16], loc[16];
    #pragma unroll
    for (int j = 0; j < 16; ++j) {
        int o = threadIdx.x + j * 256;
        bk[j] = -1;
        if (o < n) {
            int s = src[base + o];
            int d = dst[base + o];
            bk[j]  = d >> BSH;
            v[j]   = ((unsigned int)(d & (BNODES - 1)) << 17) | (unsigned int)s;
            loc[j] = atomicAdd(&cnt[bk[j]], 1);
        }
    }
    __syncthreads();
    if (threadIdx.x == 0) {
        int run = 0;
        for (int b = 0; b < NBKT; ++b) { lofs[b] = run; run += cnt[b]; }
    }
    __syncthreads();
    if (threadIdx.x < NBKT && cnt[threadIdx.x] > 0)
        gofs[threadIdx.x] = atomicAdd(&ccur[threadIdx.x], cnt[threadIdx.x]);
    __syncthreads();
    #pragma unroll
    for (int j = 0; j < 16; ++j)
        if (bk[j] >= 0) {
            int p = lofs[bk[j]] + loc[j];
            buf[p]  = v[j];
            bktA[p] = (unsigned char)bk[j];
        }
    __syncthreads();
    for (int i = threadIdx.x; i < n; i += 256) {
        int b = bktA[i];
        tmp[gofs[b] + (i - lofs[b])] = buf[i];
    }
}

// ---------------- pass 2: per-bucket LDS pipeline, PADDED CSR output ----------------
// Each bucket owns sorted region [b*SCAP, ...). Per node: edges padded to mult of 8
// with ZROW entries. offsets[d] = start; npad8[d] = padded_len/8.
__global__ __launch_bounds__(512) void bucket_kernel(const unsigned int* __restrict__ tmp,
                                                     const int* __restrict__ ccur,
                                                     int* __restrict__ offsets,
                                                     unsigned char* __restrict__ npad8,
                                                     int* __restrict__ sorted_src,
                                                     float* __restrict__ dinv1,
                                                     float* __restrict__ dinv2, int N) {
    __shared__ int cnt[BNODES];
    __shared__ int sd[512];
    int b   = blockIdx.x;
    int tid = threadIdx.x;
    int tbeg = b * BCAP, tend = ccur[b];   // bucket's run in tmp (slack layout)
    int sbase = b * SCAP;                  // bucket's region in sorted_src

    for (int i = tid; i < BNODES; i += 512) cnt[i] = 0;
    __syncthreads();
    for (int i = tbeg + tid; i < tend; i += 512)
        atomicAdd(&cnt[tmp[i] >> 17], 1);
    __syncthreads();

    int c0 = cnt[2 * tid], c1 = cnt[2 * tid + 1];
    int p0 = (c0 + 7) & ~7, p1 = (c1 + 7) & ~7;   // padded lengths
    int s  = p0 + p1;
    sd[tid] = s;
    __syncthreads();
    for (int off = 1; off < 512; off <<= 1) {
        int t = (tid >= off) ? sd[tid - off] : 0;
        __syncthreads();
        sd[tid] += t;
        __syncthreads();
    }
    int ex = sd[tid] - s;
    int g0 = sbase + ex, g1 = sbase + ex + p0;

    int node0 = b * BNODES + 2 * tid;
    if (node0 < N) {
        offsets[node0] = g0;
        npad8[node0] = (unsigned char)(p0 >> 3);
        dinv1[node0] = rsqrtf((float)(c0 + 1));
        dinv2[node0] = c0 ? rsqrtf((float)c0) : 0.0f;
        for (int k = c0; k < p0; ++k) sorted_src[g0 + k] = ZROW;   // pad fill
    }
    if (node0 + 1 < N) {
        offsets[node0 + 1] = g1;
        npad8[node0 + 1] = (unsigned char)(p1 >> 3);
        dinv1[node0 + 1] = rsqrtf((float)(c1 + 1));
        dinv2[node0 + 1] = c1 ? rsqrtf((float)c1) : 0.0f;
        for (int k = c1; k < p1; ++k) sorted_src[g1 + k] = ZROW;   // pad fill
    }
    __syncthreads();
    cnt[2 * tid] = g0;                     // absolute cursors
    cnt[2 * tid + 1] = g1;
    __syncthreads();

    for (int i = tbeg + tid; i < tend; i += 512) {
        unsigned int v = tmp[i];
        int p = atomicAdd(&cnt[v >> 17], 1);
        sorted_src[p] = (int)(v & 0x1FFFFu);
    }
}

// ---------------- MFMA GEMM: Xs = bf16((in_feat @ W1) * dinv1), 4 tiles/wave ----------------
__global__ __launch_bounds__(256) void gemm_kernel(const float* __restrict__ A,
                                                   const uint4* __restrict__ wfrag,
                                                   const float* __restrict__ dinv1,
                                                   unsigned short* __restrict__ Xs, int nTiles) {
    int wid = blockIdx.x * 4 + (threadIdx.x >> 6);
    int lane = threadIdx.x & 63;
    int lrow = lane & 15, lk = lane >> 4;

    short8 wf[16];
    #pragma unroll
    for (int i = 0; i < 16; ++i)
        wf[i] = *reinterpret_cast<const short8*>(&wfrag[i * 64 + lane]);

    #pragma unroll
    for (int tt = 0; tt < 4; ++tt) {
        int t = wid * 4 + tt;
        if (t >= nTiles) break;
        int node = t * 16 + lrow;
        const float4* ap = reinterpret_cast<const float4*>(A + (size_t)node * IN_F);

        short8 af[4];
        #pragma unroll
        for (int kc = 0; kc < 4; ++kc) {
            float4 x = ap[kc * 8 + lk * 2];
            float4 y = ap[kc * 8 + lk * 2 + 1];
            U16x8 u;
            u.us[0] = f2bf(x.x); u.us[1] = f2bf(x.y); u.us[2] = f2bf(x.z); u.us[3] = f2bf(x.w);
            u.us[4] = f2bf(y.x); u.us[5] = f2bf(y.y); u.us[6] = f2bf(y.z); u.us[7] = f2bf(y.w);
            af[kc] = u.v;
        }

        float dv = dinv1[node];
        #pragma unroll
        for (int ct = 0; ct < 4; ++ct) {
            floatx4 acc = {0.f, 0.f, 0.f, 0.f};
            acc = __builtin_amdgcn_mfma_f32_16x16x32_bf16(wf[ct * 4 + 0], af[0], acc, 0, 0, 0);
            acc = __builtin_amdgcn_mfma_f32_16x16x32_bf16(wf[ct * 4 + 1], af[1], acc, 0, 0, 0);
            acc = __builtin_amdgcn_mfma_f32_16x16x32_bf16(wf[ct * 4 + 2], af[2], acc, 0, 0, 0);
            acc = __builtin_amdgcn_mfma_f32_16x16x32_bf16(wf[ct * 4 + 3], af[3], acc, 0, 0, 0);
            uint2 o;
            o.x = pk2(acc[0] * dv, acc[1] * dv);
            o.y = pk2(acc[2] * dv, acc[3] * dv);
            *reinterpret_cast<uint2*>(Xs + (size_t)node * H_F + ct * 16 + lk * 4) = o;
        }
    }
}

// ---------------- prop1: 4 nodes/wave, padded CSR, direct uniform id loads ----------------
// h1[d] = dinv1[d]*(sum Xs[s] + Xs[d]);  h1s[d] = h1[d]*dinv2[d]
__global__ __launch_bounds__(256) void prop1_kernel(const int* __restrict__ offsets,
                                                    const unsigned char* __restrict__ npad8,
                                                    const int* __restrict__ sorted_src,
                                                    const unsigned short* __restrict__ Xs,
                                                    const float* __restrict__ dinv1,
                                                    const float* __restrict__ dinv2,
                                                    unsigned short* __restrict__ h1,
                                                    unsigned short* __restrict__ h1s, int N) {
    int wid  = (blockIdx.x * blockDim.x + threadIdx.x) >> 6;
    int lane = threadIdx.x & 63;
    int g = lane >> 4, fl = lane & 15;
    int d = wid * 4 + g;
    bool active = d < N;
    int dd = active ? d : N - 1;

    int beg = offsets[dd];
    int nit = npad8[dd];
    const int* idp = sorted_src + beg;
    const char* XsB = (const char*)Xs;
    unsigned bo = (unsigned)(fl << 3);          // byte offset within 128B row
    float c0 = 0.f, c1 = 0.f, c2 = 0.f, c3 = 0.f;

    for (int it = 0; it < nit; ++it, idp += 8) {
        int s[8]; uint2 v[8];
        #pragma unroll
        for (int j = 0; j < 8; ++j) s[j] = idp[j];          // group-uniform, L1 broadcast
        #pragma unroll
        for (int j = 0; j < 8; ++j)
            v[j] = *reinterpret_cast<const uint2*>(XsB + (((unsigned)s[j] << 7) + bo));
        #pragma unroll
        for (int j = 0; j < 8; ++j) {
            c0 += bflo(v[j].x); c1 += bfhi(v[j].x); c2 += bflo(v[j].y); c3 += bfhi(v[j].y);
        }
    }

    float dv  = dinv1[dd];
    float dv2 = dinv2[dd];
    uint2 sv = *reinterpret_cast<const uint2*>(XsB + (((unsigned)dd << 7) + bo));
    float h0  = dv * (c0 + bflo(sv.x));
    float h1v = dv * (c1 + bfhi(sv.x));
    float h2  = dv * (c2 + bflo(sv.y));
    float h3  = dv * (c3 + bfhi(sv.y));
    if (active) {
        uint2 o1; o1.x = pk2(h0, h1v); o1.y = pk2(h2, h3);
        *reinterpret_cast<uint2*>(h1 + ((size_t)d << 6) + (fl << 2)) = o1;
        uint2 o2; o2.x = pk2(h0 * dv2, h1v * dv2); o2.y = pk2(h2 * dv2, h3 * dv2);
        *reinterpret_cast<uint2*>(h1s + ((size_t)d << 6) + (fl << 2)) = o2;
    }
}

// ---------------- prop2: 4 nodes/wave, padded CSR + alpha combine ----------------
// out[d] = a0*h1[d] + a1*dinv2[d]*sum(h1s[s])
__global__ __launch_bounds__(256) void prop2_kernel(const int* __restrict__ offsets,
                                                    const unsigned char* __restrict__ npad8,
                                                    const int* __restrict__ sorted_src,
                                                    const unsigned short* __restrict__ h1,
                                                    const unsigned short* __restrict__ h1s,
                                                    const float* __restrict__ dinv2,
                                                    const float* __restrict__ alphas,
                                                    float* __restrict__ out, int N) {
    int wid  = (blockIdx.x * blockDim.x + threadIdx.x) >> 6;
    int lane = threadIdx.x & 63;
    int g = lane >> 4, fl = lane & 15;
    int d = wid * 4 + g;
    bool active = d < N;
    int dd = active ? d : N - 1;

    float e0 = expf(alphas[0]), e1 = expf(alphas[1]);
    float aw0 = e0 / (e0 + e1), aw1 = e1 / (e0 + e1);

    int beg = offsets[dd];
    int nit = npad8[dd];
    const int* idp = sorted_src + beg;
    const char* HB = (const char*)h1s;
    unsigned bo = (unsigned)(fl << 3);
    float c0 = 0.f, c1 = 0.f, c2 = 0.f, c3 = 0.f;

    for (int it = 0; it < nit; ++it, idp += 8) {
        int s[8]; uint2 v[8];
        #pragma unroll
        for (int j = 0; j < 8; ++j) s[j] = idp[j];
        #pragma unroll
        for (int j = 0; j < 8; ++j)
            v[j] = *reinterpret_cast<const uint2*>(HB + (((unsigned)s[j] << 7) + bo));
        #pragma unroll
        for (int j = 0; j < 8; ++j) {
            c0 += bflo(v[j].x); c1 += bfhi(v[j].x); c2 += bflo(v[j].y); c3 += bfhi(v[j].y);
        }
    }

    if (active) {
        float sa1 = aw1 * dinv2[dd];
        uint2 sv = *reinterpret_cast<const uint2*>((const char*)h1 + (((unsigned)d << 7) + bo));
        float4 o;
        o.x = aw0 * bflo(sv.x) + sa1 * c0;
        o.y = aw0 * bfhi(sv.x) + sa1 * c1;
        o.z = aw0 * bflo(sv.y) + sa1 * c2;
        o.w = aw0 * bfhi(sv.y) + sa1 * c3;
        *reinterpret_cast<float4*>(out + ((size_t)d << 6) + (fl << 2)) = o;
    }
}

extern "C" void kernel_launch(void* const* d_in, const int* in_sizes, int n_in,
                              void* d_out, int out_size, void* d_ws, size_t ws_size,
                              hipStream_t stream) {
    const int*   edge_index = (const int*)d_in[0];   // [2, E]
    const float* in_feat    = (const float*)d_in[1]; // [N, 128]
    const float* W1         = (const float*)d_in[2]; // [128, 64]
    const float* alphas     = (const float*)d_in[3]; // [2]
    float*       out        = (float*)d_out;         // [N, 64]

    const int* src = edge_index;
    const int* dst = edge_index + N_EDGES;

    // workspace layout (bf16 tables: (N+16) rows of 64 bf16; row N = zero sentinel)
    char* ws = (char*)d_ws;
    size_t tabBytes = (size_t)(N_NODES + 16) * H_F * 2;
    unsigned short* Xs  = (unsigned short*)(ws);                 // 12.8 MB
    unsigned int*   tmp = (unsigned int*)(ws);                   // 7.84 MB — aliases Xs rows; sentinel untouched
    unsigned short* h1  = (unsigned short*)(ws + tabBytes);      // 12.8 MB
    unsigned short* h1s = (unsigned short*)(ws + 2 * tabBytes);  // 12.8 MB
    char* p = ws + 3 * tabBytes;
    int*   sorted = (int*)p;   p += (size_t)NBKT * SCAP * 4;     // 11.05 MB (per-bucket slack)
    int*   offs   = (int*)p;   p += (size_t)(N_NODES + 4) * 4;
    float* dinv1  = (float*)p; p += (size_t)N_NODES * 4;
    float* dinv2  = (float*)p; p += (size_t)N_NODES * 4;
    unsigned char* npad8 = (unsigned char*)p; p += (size_t)(N_NODES + 64);
    p = (char*)(((size_t)p + 63) & ~(size_t)63);
    int*   ccur   = (int*)p;   p += (size_t)NBKT * 4;
    unsigned int* wfrag = (unsigned int*)p; p += 8192 * 4;       // 32 KB packed W frags

    initwpack_kernel<<<32, 256, 0, stream>>>(W1, wfrag, ccur,
                                             (unsigned int*)(Xs + (size_t)N_NODES * H_F),
                                             (unsigned int*)(h1s + (size_t)N_NODES * H_F));
    coarse_scatter_kernel<<<(N_EDGES + EPB - 1) / EPB, 256, 0, stream>>>(src, dst, ccur, tmp, N_EDGES);
    bucket_kernel<<<NBKT, 512, 0, stream>>>(tmp, ccur, offs, npad8, sorted, dinv1, dinv2, N_NODES);

    // gemm after bucket_kernel (tmp aliases Xs; needs dinv1)
    int nTiles = N_NODES / 16;                        // 6250
    int gemm_waves = (nTiles + 3) / 4;                // 1563
    gemm_kernel<<<(gemm_waves + 3) / 4, 256, 0, stream>>>(in_feat, (const uint4*)wfrag, dinv1, Xs, nTiles);

    int pwaves  = (N_NODES + 3) / 4;                  // 25000 waves, 4 nodes each
    int pblocks = (pwaves + 3) / 4;                   // 6250 blocks of 256
    prop1_kernel<<<pblocks, 256, 0, stream>>>(offs, npad8, sorted, Xs, dinv1, dinv2, h1, h1s, N_NODES);
    prop2_kernel<<<pblocks, 256, 0, stream>>>(offs, npad8, sorted, h1, h1s, dinv2, alphas, out, N_NODES);
}